// Round 1
// baseline (8238.535 us; speedup 1.0000x reference)
//
#include <hip/hip_runtime.h>
#include <math.h>

#define B_  64
#define LW  512
#define H_  64
#define NL_ 8

__device__ __forceinline__ float sigmoidf_(float x) {
    return 1.0f / (1.0f + expf(-x));
}

// ---------------- prep: transpose weights into ws ----------------
// ws layout (floats):
//   wT_ih [8][64][192]  @ 0        (98304)   wT_ih[l][k][o] = w_ih[l][o][k]
//   wT_hh [8][64][192]  @ 98304    (98304)
//   wT1   [8][64][64]   @ 196608   (32768)
//   wT2   [8][32][32]   @ 229376   (8192)
//   wT3   [8][32][32]   @ 237568   (8192)
//   wT4   [8][128][64]  @ 245760   (65536)
// total 311296 floats = 1.19 MB
__global__ __launch_bounds__(256) void prep_kernel(
    const float* __restrict__ w_ih, const float* __restrict__ w_hh,
    const float* __restrict__ aw1, const float* __restrict__ aw2,
    const float* __restrict__ aw3, const float* __restrict__ aw4,
    float* __restrict__ ws)
{
    int i = blockIdx.x * 256 + threadIdx.x;
    if (i < 98304) {
        int l = i / 12288, r = i % 12288, k = r / 192, o = r % 192;
        ws[i] = w_ih[l*12288 + o*64 + k];
    } else if (i < 196608) {
        int j = i - 98304;
        int l = j / 12288, r = j % 12288, k = r / 192, o = r % 192;
        ws[i] = w_hh[l*12288 + o*64 + k];
    } else if (i < 229376) {
        int j = i - 196608;
        int l = j / 4096, r = j % 4096, k = r / 64, o = r % 64;
        ws[i] = aw1[l*4096 + o*64 + k];
    } else if (i < 237568) {
        int j = i - 229376;
        int l = j / 1024, r = j % 1024, k = r / 32, o = r % 32;
        ws[i] = aw2[l*1024 + o*32 + k];
    } else if (i < 245760) {
        int j = i - 237568;
        int l = j / 1024, r = j % 1024, k = r / 32, o = r % 32;
        ws[i] = aw3[l*1024 + o*32 + k];
    } else if (i < 311296) {
        int j = i - 245760;
        int l = j / 8192, r = j % 8192, k = r / 64, o = r % 64;
        ws[i] = aw4[l*8192 + o*128 + k];
    }
}

// ---------------- recurrence: wavefront over 8 layers ----------------
// grid = 64 (one WG per batch), block = 512 (wave i = layer i)
__global__ __launch_bounds__(512) void rnn_kernel(
    const float* __restrict__ x, const float* __restrict__ h0,
    const float* __restrict__ b_ih, const float* __restrict__ b_hh,
    const float* __restrict__ ws,
    float* __restrict__ ys_out, float* __restrict__ hfin_out)
{
    const int b  = blockIdx.x;
    const int wv = threadIdx.x >> 6;   // layer
    const int ln = threadIdx.x & 63;

    __shared__ float hbuf[8][64];       // per-layer hidden (post-attn)
    __shared__ float obuf[2][9][64];    // slot j = input for layer j; dbl-buffered
    __shared__ float se[8][2][64];      // per-wave: [h, sorted h]
    __shared__ float abuf[8][2][128];   // per-wave attn scratch

    const float* WihT = ws + wv*12288;
    const float* WhhT = ws + 98304  + wv*12288;
    const float* W1T  = ws + 196608 + wv*4096;
    const float* W2T  = ws + 229376 + wv*1024;
    const float* W3T  = ws + 237568 + wv*1024;
    const float* W4T  = ws + 245760 + wv*8192;

    const float bi_r = b_ih[wv*192 + ln];
    const float bi_z = b_ih[wv*192 + 64 + ln];
    const float bi_n = b_ih[wv*192 + 128 + ln];
    const float bh_r = b_hh[wv*192 + ln];
    const float bh_z = b_hh[wv*192 + 64 + ln];
    const float bh_n = b_hh[wv*192 + 128 + ln];

    hbuf[wv][ln] = h0[wv*64 + ln];

    float xreg = 0.0f;
    if (wv == 0) xreg = x[b*32768 + ln];   // prefetch t=0

    const int o1 = ln & 31;
    const int i1 = ln >> 5;

    for (int s = 0; s < LW + NL_ - 1; ++s) {
        const int rb = (s + 1) & 1;   // buffer read this step
        const int wb = s & 1;         // buffer written this step
        if (wv == 0 && s < LW) {
            obuf[rb][0][ln] = xreg;
            if (s + 1 < LW) xreg = x[b*32768 + (s+1)*64 + ln];
        }
        __syncthreads();
        const int t = s - wv;
        if (t >= 0 && t < LW) {
            const float* inp  = &obuf[rb][wv][0];
            const float* hrow = &hbuf[wv][0];

            // ---- GRU gates ----
            float accr = bi_r, accz = bi_z, accn = bi_n;
            float ghr = bh_r, ghz = bh_z, ghn = bh_n;
            #pragma unroll 4
            for (int k = 0; k < 64; k += 4) {
                const float4 i4 = *(const float4*)(inp + k);
                const float4 h4 = *(const float4*)(hrow + k);
                const float iv[4] = {i4.x, i4.y, i4.z, i4.w};
                const float hv[4] = {h4.x, h4.y, h4.z, h4.w};
                #pragma unroll
                for (int u = 0; u < 4; ++u) {
                    const float* wi = WihT + (k+u)*192;
                    const float* wh = WhhT + (k+u)*192;
                    accr = fmaf(wi[ln],     iv[u], accr);
                    accz = fmaf(wi[64+ln],  iv[u], accz);
                    accn = fmaf(wi[128+ln], iv[u], accn);
                    ghr  = fmaf(wh[ln],     hv[u], ghr);
                    ghz  = fmaf(wh[64+ln],  hv[u], ghz);
                    ghn  = fmaf(wh[128+ln], hv[u], ghn);
                }
            }
            const float hown = hrow[ln];
            const float r = sigmoidf_(accr + ghr);
            const float z = sigmoidf_(accz + ghz);
            const float n = tanhf(accn + r * ghn);
            const float hg = (1.0f - z) * n + z * hown;

            // ---- bitonic ascending sort across 64 lanes ----
            float v = hg;
            #pragma unroll
            for (int kk = 2; kk <= 64; kk <<= 1) {
                #pragma unroll
                for (int j = kk >> 1; j > 0; j >>= 1) {
                    float ov = __shfl_xor(v, j);
                    float mn = fminf(v, ov), mx = fmaxf(v, ov);
                    bool keepmin = (((ln & kk) == 0) == ((ln & j) == 0));
                    v = keepmin ? mn : mx;
                }
            }
            se[wv][0][ln] = hg;
            se[wv][1][ln] = v;
            asm volatile("s_waitcnt lgkmcnt(0)" ::: "memory");

            // ---- a1 = se @ w1.T  (lane = output col, both rows) ----
            float a10 = 0.f, a11 = 0.f;
            #pragma unroll 4
            for (int k = 0; k < 64; k += 4) {
                const float4 s0 = *(const float4*)(&se[wv][0][k]);
                const float4 s1 = *(const float4*)(&se[wv][1][k]);
                const float sv0[4] = {s0.x, s0.y, s0.z, s0.w};
                const float sv1[4] = {s1.x, s1.y, s1.z, s1.w};
                #pragma unroll
                for (int u = 0; u < 4; ++u) {
                    float w = W1T[(k+u)*64 + ln];
                    a10 = fmaf(w, sv0[u], a10);
                    a11 = fmaf(w, sv1[u], a11);
                }
            }
            abuf[wv][0][ln]      = a10;   // a1 flat[ln]
            abuf[wv][0][64+ln]   = a11;   // a1 flat[64+ln]
            asm volatile("s_waitcnt lgkmcnt(0)" ::: "memory");

            // ---- a2 = shuffle(a1.view(4,32)) @ w2.T ----
            float p0 = 0.f, p1 = 0.f;
            #pragma unroll
            for (int k = 0; k < 32; ++k) {
                float w = W2T[k*32 + o1];
                int idx = (k & 3)*32 + i1*8 + (k >> 2);
                p0 = fmaf(abuf[wv][0][idx],      w, p0);
                p1 = fmaf(abuf[wv][0][idx + 16], w, p1);
            }
            abuf[wv][1][ln]    = p0;   // flat f = ln
            abuf[wv][1][64+ln] = p1;   // flat f = 64+ln
            asm volatile("s_waitcnt lgkmcnt(0)" ::: "memory");

            // ---- a3 = relu(shuffle(a2) @ w3.T) ----
            float c0 = 0.f, c1 = 0.f;
            #pragma unroll
            for (int k = 0; k < 32; ++k) {
                float w = W3T[k*32 + o1];
                int idx = (k & 3)*32 + i1*8 + (k >> 2);
                c0 = fmaf(abuf[wv][1][idx],      w, c0);
                c1 = fmaf(abuf[wv][1][idx + 16], w, c1);
            }
            abuf[wv][0][ln]    = fmaxf(c0, 0.f);
            abuf[wv][0][64+ln] = fmaxf(c1, 0.f);
            asm volatile("s_waitcnt lgkmcnt(0)" ::: "memory");

            // ---- scores = sigmoid(a3.flat(128) @ w4.T), h *= scores ----
            float sc = 0.f;
            #pragma unroll 4
            for (int k = 0; k < 128; k += 4) {
                const float4 a4 = *(const float4*)(&abuf[wv][0][k]);
                const float av[4] = {a4.x, a4.y, a4.z, a4.w};
                #pragma unroll
                for (int u = 0; u < 4; ++u)
                    sc = fmaf(W4T[(k+u)*64 + ln], av[u], sc);
            }
            const float hat = hg * sigmoidf_(sc);

            hbuf[wv][ln] = hat;
            obuf[wb][wv+1][ln] = hat;
            if (wv == 7) ys_out[(b*LW + t)*64 + ln] = hat;
            if (t == LW - 1) hfin_out[(wv*64 + b)*64 + ln] = hat;
        }
    }
}

// ---------------- heads: per-window seg + cls logits ----------------
__global__ __launch_bounds__(256) void heads_kernel(
    const float* __restrict__ ys,
    const float* __restrict__ sw1, const float* __restrict__ sb1,
    const float* __restrict__ sw2, const float* __restrict__ sb2,
    const float* __restrict__ sw3, const float* __restrict__ sb3,
    const float* __restrict__ sw4, const float* __restrict__ sb4,
    const float* __restrict__ cw1, const float* __restrict__ cb1,
    const float* __restrict__ cw2, const float* __restrict__ cb2,
    const float* __restrict__ cw3, const float* __restrict__ cb3,
    const float* __restrict__ cw4, const float* __restrict__ cb4,
    float* __restrict__ seg_out, float* __restrict__ cls_tmp)
{
    const int idx = blockIdx.x * 256 + threadIdx.x;
    if (idx >= B_ * LW) return;
    const int b = idx >> 9, t = idx & 511;

    float y[64];
    const float4* yp = (const float4*)(ys + idx*64);
    #pragma unroll
    for (int i = 0; i < 16; ++i) {
        float4 v = yp[i];
        y[4*i+0] = v.x; y[4*i+1] = v.y; y[4*i+2] = v.z; y[4*i+3] = v.w;
    }

    float t1[8][4], t2[8][4], t3[8][4];

    // ======== seg head ========
    #pragma unroll
    for (int g = 0; g < 8; ++g)
        #pragma unroll
        for (int s = 0; s < 4; ++s) {
            float acc = sb1[s];
            #pragma unroll
            for (int k = 0; k < 8; ++k) acc = fmaf(y[g*8+k], sw1[s*8+k], acc);
            t1[g][s] = acc;
        }
    #pragma unroll
    for (int i = 0; i < 8; ++i) {
        float sh[4];
        #pragma unroll
        for (int j = 0; j < 4; ++j) { int m = i*4+j; sh[j] = t1[m & 7][m >> 3]; }
        #pragma unroll
        for (int s = 0; s < 4; ++s) {
            float acc = sb2[s];
            #pragma unroll
            for (int j = 0; j < 4; ++j) acc = fmaf(sh[j], sw2[s*4+j], acc);
            t2[i][s] = acc;
        }
    }
    #pragma unroll
    for (int i = 0; i < 8; ++i) {
        float sh[4];
        #pragma unroll
        for (int j = 0; j < 4; ++j) { int m = i*4+j; sh[j] = t2[m & 7][m >> 3]; }
        #pragma unroll
        for (int s = 0; s < 4; ++s) {
            float acc = sb3[s];
            #pragma unroll
            for (int j = 0; j < 4; ++j) acc = fmaf(sh[j], sw3[s*4+j], acc);
            t3[i][s] = acc;
        }
    }
    #pragma unroll
    for (int w = 0; w < 16; ++w) {
        float o4[4];
        #pragma unroll
        for (int s = 0; s < 4; ++s) {
            float acc = sb4[w];
            #pragma unroll
            for (int j = 0; j < 8; ++j) {
                int f = s*8+j;
                acc = fmaf(t3[f >> 2][f & 3], sw4[w*8+j], acc);
            }
            o4[s] = acc;
        }
        float4 vv = {o4[0], o4[1], o4[2], o4[3]};
        ((float4*)seg_out)[b*8192 + t*16 + w] = vv;
    }

    // ======== cls head ========
    #pragma unroll
    for (int g = 0; g < 8; ++g)
        #pragma unroll
        for (int s = 0; s < 4; ++s) {
            float acc = cb1[s];
            #pragma unroll
            for (int k = 0; k < 8; ++k) acc = fmaf(y[g*8+k], cw1[s*8+k], acc);
            t1[g][s] = acc;
        }
    #pragma unroll
    for (int i = 0; i < 8; ++i) {
        float sh[4];
        #pragma unroll
        for (int j = 0; j < 4; ++j) { int m = i*4+j; sh[j] = t1[m & 7][m >> 3]; }
        #pragma unroll
        for (int s = 0; s < 4; ++s) {
            float acc = cb2[s];
            #pragma unroll
            for (int j = 0; j < 4; ++j) acc = fmaf(sh[j], cw2[s*4+j], acc);
            t2[i][s] = acc;
        }
    }
    #pragma unroll
    for (int i = 0; i < 8; ++i) {
        float sh[4];
        #pragma unroll
        for (int j = 0; j < 4; ++j) { int m = i*4+j; sh[j] = t2[m & 7][m >> 3]; }
        #pragma unroll
        for (int s = 0; s < 4; ++s) {
            float acc = cb3[s];
            #pragma unroll
            for (int j = 0; j < 4; ++j) acc = fmaf(sh[j], cw3[s*4+j], acc);
            t3[i][s] = fmaxf(acc, 0.f);
        }
    }
    float cc[4];
    #pragma unroll
    for (int c = 0; c < 4; ++c) {
        float acc = cb4[c];
        #pragma unroll
        for (int k = 0; k < 32; ++k)
            acc = fmaf(t3[k >> 2][k & 3], cw4[c*32+k], acc);
        cc[c] = acc;
    }
    float4 cv = {cc[0], cc[1], cc[2], cc[3]};
    ((float4*)cls_tmp)[idx] = cv;
}

// ---------------- cls mean over windows ----------------
__global__ __launch_bounds__(256) void cls_reduce_kernel(
    const float* __restrict__ cls_tmp, float* __restrict__ cls_out)
{
    const int tid = threadIdx.x;       // 256 threads: (b, quarter)
    const int b = tid >> 2, q = tid & 3;
    float ax = 0.f, ay = 0.f, az = 0.f, aw = 0.f;
    for (int t = q; t < 512; t += 4) {
        float4 v = ((const float4*)cls_tmp)[b*512 + t];
        ax += v.x; ay += v.y; az += v.z; aw += v.w;
    }
    ax += __shfl_xor(ax, 1); ay += __shfl_xor(ay, 1);
    az += __shfl_xor(az, 1); aw += __shfl_xor(aw, 1);
    ax += __shfl_xor(ax, 2); ay += __shfl_xor(ay, 2);
    az += __shfl_xor(az, 2); aw += __shfl_xor(aw, 2);
    if (q == 0) {
        float4 rv = {ax/512.f, ay/512.f, az/512.f, aw/512.f};
        ((float4*)cls_out)[b] = rv;
    }
}

// ---------------- avg_pool1d(k=11,s=1) with 10 zero history ----------------
__global__ __launch_bounds__(256) void pool_kernel(
    const float* __restrict__ seg, float* __restrict__ pool_out)
{
    const int idx = blockIdx.x * 256 + threadIdx.x;  // (b, l)
    if (idx >= B_ * 8192) return;
    const int b = idx >> 13, l = idx & 8191;
    float ax = 0.f, ay = 0.f, az = 0.f, aw = 0.f;
    int j0 = l - 10; if (j0 < 0) j0 = 0;
    for (int j = j0; j <= l; ++j) {
        float4 v = ((const float4*)seg)[b*8192 + j];
        ax += v.x; ay += v.y; az += v.z; aw += v.w;
    }
    const float inv = 1.0f / 11.0f;
    float4 ov = {ax*inv, ay*inv, az*inv, aw*inv};
    ((float4*)pool_out)[idx] = ov;
}

extern "C" void kernel_launch(void* const* d_in, const int* in_sizes, int n_in,
                              void* d_out, int out_size, void* d_ws, size_t ws_size,
                              hipStream_t stream)
{
    const float* x    = (const float*)d_in[0];
    const float* h0   = (const float*)d_in[1];
    const float* w_ih = (const float*)d_in[2];
    const float* w_hh = (const float*)d_in[3];
    const float* bih  = (const float*)d_in[4];
    const float* bhh  = (const float*)d_in[5];
    const float* aw1  = (const float*)d_in[6];
    const float* aw2  = (const float*)d_in[7];
    const float* aw3  = (const float*)d_in[8];
    const float* aw4  = (const float*)d_in[9];
    const float* sw1  = (const float*)d_in[10];
    const float* sb1  = (const float*)d_in[11];
    const float* sw2  = (const float*)d_in[12];
    const float* sb2  = (const float*)d_in[13];
    const float* sw3  = (const float*)d_in[14];
    const float* sb3  = (const float*)d_in[15];
    const float* sw4  = (const float*)d_in[16];
    const float* sb4  = (const float*)d_in[17];
    const float* cw1  = (const float*)d_in[18];
    const float* cb1  = (const float*)d_in[19];
    const float* cw2  = (const float*)d_in[20];
    const float* cb2  = (const float*)d_in[21];
    const float* cw3  = (const float*)d_in[22];
    const float* cb3  = (const float*)d_in[23];
    const float* cw4  = (const float*)d_in[24];
    const float* cb4  = (const float*)d_in[25];

    float* out      = (float*)d_out;
    float* pool_out = out;                 // (64,8192,4)
    float* cls_out  = out + 2097152;       // (64,4)
    float* ys_out   = out + 2097408;       // (64,512,64)
    float* hfin     = out + 4194560;       // (8,64,64)
    float* seg_out  = out + 4227328;       // (64,8192,4)
    float* wsf      = (float*)d_ws;        // 1.19 MB transposed weights
    float* cls_tmp  = pool_out;            // staged in pool region, overwritten last

    prep_kernel<<<1216, 256, 0, stream>>>(w_ih, w_hh, aw1, aw2, aw3, aw4, wsf);
    rnn_kernel<<<64, 512, 0, stream>>>(x, h0, bih, bhh, wsf, ys_out, hfin);
    heads_kernel<<<128, 256, 0, stream>>>(ys_out, sw1, sb1, sw2, sb2, sw3, sb3, sw4, sb4,
                                          cw1, cb1, cw2, cb2, cw3, cb3, cw4, cb4,
                                          seg_out, cls_tmp);
    cls_reduce_kernel<<<1, 256, 0, stream>>>(cls_tmp, cls_out);
    pool_kernel<<<2048, 256, 0, stream>>>(seg_out, pool_out);
}

// Round 2
// 6975.884 us; speedup vs baseline: 1.1810x; 1.1810x over previous
//
#include <hip/hip_runtime.h>
#include <math.h>

#define B_  64
#define LW  512
#define NL_ 8

typedef unsigned short u16;
typedef float f32x4 __attribute__((ext_vector_type(4)));
typedef u16 u16x4 __attribute__((ext_vector_type(4)));
typedef u16 u16x8 __attribute__((ext_vector_type(8)));
typedef unsigned u32x4v __attribute__((ext_vector_type(4)));
typedef __bf16 bf16x8 __attribute__((ext_vector_type(8)));

__device__ __forceinline__ u16 f2bf(float f) {
    unsigned u = __builtin_bit_cast(unsigned, f);
    unsigned r = (u + 0x7fffu + ((u >> 16) & 1u)) >> 16;
    return (u16)r;
}
__device__ __forceinline__ float bf2f(u16 h) {
    unsigned u = ((unsigned)h) << 16;
    return __builtin_bit_cast(float, u);
}
__device__ __forceinline__ float sigm(float x) {
    return __builtin_amdgcn_rcpf(1.0f + __expf(-x));
}
__device__ __forceinline__ float tanhfast(float x) {
    return 1.0f - 2.0f * __builtin_amdgcn_rcpf(1.0f + __expf(2.0f * x));
}
__device__ __forceinline__ f32x4 mfma16(u16x8 a, u16x8 b, f32x4 c) {
    return __builtin_amdgcn_mfma_f32_16x16x32_bf16(
        __builtin_bit_cast(bf16x8, a), __builtin_bit_cast(bf16x8, b), c, 0, 0, 0);
}
__device__ __forceinline__ u16x8 ld8_8al(const u16* p) {   // 8B-aligned 16B load
    u16x4 lo = *(const u16x4*)p;
    u16x4 hi = *(const u16x4*)(p + 4);
    return __builtin_shufflevector(lo, hi, 0, 1, 2, 3, 4, 5, 6, 7);
}

// zero the flag header of ws (wflag[7][16] + rdone[8] + padding -> 256 u32)
__global__ __launch_bounds__(256) void init_flags(unsigned* ws) {
    ws[threadIdx.x] = 0u;
}

// ---------------- recurrence: one block per layer, batch-GEMM via MFMA ----------------
// grid = 8, block = 512. Weights bf16 resident in LDS. Layers pipeline via 16-deep
// global ring (agent-scope acquire/release flags).
__global__ __launch_bounds__(512) void rnn_kernel(
    const float* __restrict__ x, const float* __restrict__ h0,
    const float* __restrict__ w_ih, const float* __restrict__ w_hh,
    const float* __restrict__ bih, const float* __restrict__ bhh,
    const float* __restrict__ aw1, const float* __restrict__ aw2,
    const float* __restrict__ aw3, const float* __restrict__ aw4,
    float* __restrict__ ys, float* __restrict__ hfin,
    unsigned* __restrict__ flags, u16* __restrict__ ring)
{
    const int l   = blockIdx.x;
    const int tid = threadIdx.x;
    const int w   = tid >> 6;
    const int ln  = tid & 63;
    const int l15 = ln & 15;
    const int l4  = ln >> 4;

    unsigned* wflag = flags;        // [7][16]
    unsigned* rdone = flags + 112;  // [8]

    // LDS: 156,672 B total
    __shared__ __align__(16) u16  Wrz[128][136];  // rows: [r(0..63), z(64..127)]; cols: [ih(0..63)|hh(64..127)]
    __shared__ __align__(16) u16  Wni[64][72];    // n-gate, ih part
    __shared__ __align__(16) u16  Wnh[64][72];    // n-gate, hh part
    __shared__ __align__(16) u16  W1s[64][72];
    __shared__ __align__(16) u16  W2s[32][40];
    __shared__ __align__(16) u16  W3s[32][40];
    __shared__ __align__(16) u16  W4s[64][136];
    __shared__ __align__(16) u16  Hin[64][72];    // staged layer input (bf16)
    __shared__ __align__(16) u16  hbf[64][72];    // h state (bf16, GRU A-operand)
    __shared__ __align__(16) float h32[64][68];   // h state / hg (f32 master)
    __shared__ __align__(16) u16  pool[18432 / 2];// se[r*72+c] (r<128)  OVERLAY  a2A/a3A[R*36+c] (R<256)
    __shared__ __align__(16) u16  w4A[64][136];   // flattened relu(a3) per batch (128 wide)

    // ---- prologue: stage weights f32->bf16 into LDS ----
    for (int i = tid; i < 128 * 128; i += 512) {
        int n = i >> 7, k = i & 127;
        float v = (k < 64) ? w_ih[l * 12288 + n * 64 + k]
                           : w_hh[l * 12288 + n * 64 + (k - 64)];
        Wrz[n][k] = f2bf(v);
    }
    for (int i = tid; i < 4096; i += 512) {
        int n = i >> 6, k = i & 63;
        Wni[n][k] = f2bf(w_ih[l * 12288 + (128 + n) * 64 + k]);
        Wnh[n][k] = f2bf(w_hh[l * 12288 + (128 + n) * 64 + k]);
        W1s[n][k] = f2bf(aw1[l * 4096 + n * 64 + k]);
    }
    for (int i = tid; i < 1024; i += 512) {
        int n = i >> 5, k = i & 31;
        W2s[n][k] = f2bf(aw2[l * 1024 + n * 32 + k]);
        W3s[n][k] = f2bf(aw3[l * 1024 + n * 32 + k]);
    }
    for (int i = tid; i < 8192; i += 512) {
        int n = i >> 7, k = i & 127;
        W4s[n][k] = f2bf(aw4[l * 8192 + n * 128 + k]);
    }
    for (int i = tid; i < 4096; i += 512) {
        int b = i >> 6, o = i & 63;
        float v = h0[l * 64 + o];
        h32[b][o] = v;
        hbf[b][o] = f2bf(v);
    }

    // per-lane ownership: mt = batch strip, oth = output-col half
    const int mt  = w & 3;
    const int oth = w >> 2;   // 0..1
    float brs[2], bzs[2], bnis[2], bnhs[2];
    #pragma unroll
    for (int q = 0; q < 2; ++q) {
        int o = 16 * (2 * oth + q) + l15;
        brs[q]  = bih[l * 192 + o]       + bhh[l * 192 + o];
        bzs[q]  = bih[l * 192 + 64 + o]  + bhh[l * 192 + 64 + o];
        bnis[q] = bih[l * 192 + 128 + o];
        bnhs[q] = bhh[l * 192 + 128 + o];
    }
    __syncthreads();

    for (int t = 0; t < LW; ++t) {
        // ================= P0: acquire input =================
        if (l == 0) {
            int b = tid >> 3, c8 = (tid & 7) * 8;
            const float* xp = x + b * 32768 + t * 64 + c8;
            float4 v0 = *(const float4*)xp;
            float4 v1 = *(const float4*)(xp + 4);
            u16x8 hv;
            hv[0] = f2bf(v0.x); hv[1] = f2bf(v0.y); hv[2] = f2bf(v0.z); hv[3] = f2bf(v0.w);
            hv[4] = f2bf(v1.x); hv[5] = f2bf(v1.y); hv[6] = f2bf(v1.z); hv[7] = f2bf(v1.w);
            *(u16x8*)&Hin[b][c8] = hv;
        } else {
            const unsigned want = (unsigned)(t + 1);
            while (__hip_atomic_load(&wflag[(l - 1) * 16 + (t & 15)],
                                     __ATOMIC_ACQUIRE, __HIP_MEMORY_SCOPE_AGENT) < want)
                __builtin_amdgcn_s_sleep(2);
            const unsigned* src =
                (const unsigned*)(ring + (size_t)(l - 1) * 65536 + (size_t)(t & 15) * 4096) + tid * 4;
            unsigned d0 = __hip_atomic_load(src + 0, __ATOMIC_RELAXED, __HIP_MEMORY_SCOPE_AGENT);
            unsigned d1 = __hip_atomic_load(src + 1, __ATOMIC_RELAXED, __HIP_MEMORY_SCOPE_AGENT);
            unsigned d2 = __hip_atomic_load(src + 2, __ATOMIC_RELAXED, __HIP_MEMORY_SCOPE_AGENT);
            unsigned d3 = __hip_atomic_load(src + 3, __ATOMIC_RELAXED, __HIP_MEMORY_SCOPE_AGENT);
            u32x4v dv = {d0, d1, d2, d3};
            int b = tid >> 3, c8 = (tid & 7) * 8;
            *(u16x8*)&Hin[b][c8] = __builtin_bit_cast(u16x8, dv);
        }
        __syncthreads();   // P0e
        if (l > 0 && tid == 0)
            __hip_atomic_store(&rdone[l], (unsigned)(t + 1),
                               __ATOMIC_RELEASE, __HIP_MEMORY_SCOPE_AGENT);

        // ================= P1: GRU (all 8 waves) =================
        {
            u16x8 Ag[4];
            const int arow = 16 * mt + l15;
            Ag[0] = *(const u16x8*)&Hin[arow][l4 * 8];
            Ag[1] = *(const u16x8*)&Hin[arow][32 + l4 * 8];
            Ag[2] = *(const u16x8*)&hbf[arow][l4 * 8];
            Ag[3] = *(const u16x8*)&hbf[arow][32 + l4 * 8];
            f32x4 z4 = {0.f, 0.f, 0.f, 0.f};
            f32x4 aR[2] = {z4, z4}, aZ[2] = {z4, z4}, aNI[2] = {z4, z4}, aNH[2] = {z4, z4};
            #pragma unroll
            for (int q = 0; q < 2; ++q) {
                const int nr = 16 * (2 * oth + q) + l15;   // = o
                #pragma unroll
                for (int kk = 0; kk < 4; ++kk) {
                    aR[q] = mfma16(Ag[kk], *(const u16x8*)&Wrz[nr][kk * 32 + l4 * 8], aR[q]);
                    aZ[q] = mfma16(Ag[kk], *(const u16x8*)&Wrz[64 + nr][kk * 32 + l4 * 8], aZ[q]);
                }
                #pragma unroll
                for (int kk = 0; kk < 2; ++kk) {
                    aNI[q] = mfma16(Ag[kk],     *(const u16x8*)&Wni[nr][kk * 32 + l4 * 8], aNI[q]);
                    aNH[q] = mfma16(Ag[kk + 2], *(const u16x8*)&Wnh[nr][kk * 32 + l4 * 8], aNH[q]);
                }
            }
            #pragma unroll
            for (int q = 0; q < 2; ++q) {
                const int o = 16 * (2 * oth + q) + l15;
                #pragma unroll
                for (int j = 0; j < 4; ++j) {
                    const int b = 16 * mt + 4 * l4 + j;
                    float r  = sigm(aR[q][j] + brs[q]);
                    float zz = sigm(aZ[q][j] + bzs[q]);
                    float nn = tanhfast(aNI[q][j] + bnis[q] + r * (aNH[q][j] + bnhs[q]));
                    float hold = h32[b][o];
                    float hg = (1.0f - zz) * nn + zz * hold;
                    h32[b][o] = hg;
                    pool[b * 72 + o] = f2bf(hg);   // se row b (part 0)
                }
            }
        }
        __syncthreads();   // P1e

        // ================= P2: bitonic sort (8 rows per wave) =================
        #pragma unroll 2
        for (int p = 0; p < 8; ++p) {
            const int r = 8 * w + p;
            float v = bf2f(pool[r * 72 + ln]);
            #pragma unroll
            for (int kk = 2; kk <= 64; kk <<= 1) {
                #pragma unroll
                for (int j = kk >> 1; j > 0; j >>= 1) {
                    float ov = __shfl_xor(v, j);
                    float mn = fminf(v, ov), mx = fmaxf(v, ov);
                    bool keepmin = (((ln & kk) == 0) == ((ln & j) == 0));
                    v = keepmin ? mn : mx;
                }
            }
            pool[(64 + r) * 72 + ln] = f2bf(v);    // se row 64+r (part 1)
        }
        __syncthreads();   // P2e

        // ================= P3: a1 = se @ W1^T, shuffled into a2A =================
        {
            const int amt = w;                     // m-tile of se (0..7)
            const int srow = 16 * amt + l15;
            u16x8 A0 = *(const u16x8*)&pool[srow * 72 + l4 * 8];
            u16x8 A1 = *(const u16x8*)&pool[srow * 72 + 32 + l4 * 8];
            u16x8 Bf[4][2];
            #pragma unroll
            for (int nt = 0; nt < 4; ++nt)
                #pragma unroll
                for (int kk = 0; kk < 2; ++kk)
                    Bf[nt][kk] = *(const u16x8*)&W1s[16 * nt + l15][kk * 32 + l4 * 8];
            __syncthreads();   // P3-mid: all reads of se done before overlay writes
            f32x4 z4 = {0.f, 0.f, 0.f, 0.f};
            f32x4 c[4] = {z4, z4, z4, z4};
            #pragma unroll
            for (int nt = 0; nt < 4; ++nt) {
                c[nt] = mfma16(A0, Bf[nt][0], c[nt]);
                c[nt] = mfma16(A1, Bf[nt][1], c[nt]);
            }
            const int part = amt >> 2;
            const int bbase = 16 * (amt & 3);
            #pragma unroll
            for (int nt = 0; nt < 4; ++nt) {
                const int n = 16 * nt + l15;
                const int f = part * 64 + n;
                const int q = (f & 31) * 4 + (f >> 5);
                const int R0 = q >> 5, col = q & 31;
                #pragma unroll
                for (int j = 0; j < 4; ++j) {
                    const int b = bbase + 4 * l4 + j;
                    pool[(b * 4 + R0) * 36 + col] = f2bf(c[nt][j]);
                }
            }
        }
        __syncthreads();   // P3e

        // ================= P4: a2 ; P5: a3 (intra-wave row-local, no barrier between) ==========
        {
            const int Rb0 = 32 * w;
            u16x8 a2a[2];
            a2a[0] = ld8_8al(&pool[(Rb0 + l15) * 36 + l4 * 8]);
            a2a[1] = ld8_8al(&pool[(Rb0 + 16 + l15) * 36 + l4 * 8]);
            u16x8 B2[2], B3[2];
            #pragma unroll
            for (int nt = 0; nt < 2; ++nt) {
                B2[nt] = *(const u16x8*)&W2s[16 * nt + l15][l4 * 8];
                B3[nt] = *(const u16x8*)&W3s[16 * nt + l15][l4 * 8];
            }
            f32x4 z4 = {0.f, 0.f, 0.f, 0.f};
            f32x4 c2[2][2];
            #pragma unroll
            for (int mi = 0; mi < 2; ++mi)
                #pragma unroll
                for (int nt = 0; nt < 2; ++nt)
                    c2[mi][nt] = mfma16(a2a[mi], B2[nt], z4);
            // shuffle-write a2 -> a3A (same rows this wave read)
            #pragma unroll
            for (int mi = 0; mi < 2; ++mi)
                #pragma unroll
                for (int nt = 0; nt < 2; ++nt)
                    #pragma unroll
                    for (int j = 0; j < 4; ++j) {
                        const int m = Rb0 + 16 * mi + 4 * l4 + j;
                        const int b = m >> 2, i2 = m & 3;
                        const int n = 16 * nt + l15;
                        const int f2 = i2 * 32 + n;
                        const int q2 = (f2 & 31) * 4 + (f2 >> 5);
                        pool[(b * 4 + (q2 >> 5)) * 36 + (q2 & 31)] = f2bf(c2[mi][nt][j]);
                    }
            // a3 = relu(shuffle(a2) @ W3^T) -> w4A
            u16x8 a3a[2];
            a3a[0] = ld8_8al(&pool[(Rb0 + l15) * 36 + l4 * 8]);
            a3a[1] = ld8_8al(&pool[(Rb0 + 16 + l15) * 36 + l4 * 8]);
            f32x4 c3[2][2];
            #pragma unroll
            for (int mi = 0; mi < 2; ++mi)
                #pragma unroll
                for (int nt = 0; nt < 2; ++nt)
                    c3[mi][nt] = mfma16(a3a[mi], B3[nt], z4);
            #pragma unroll
            for (int mi = 0; mi < 2; ++mi)
                #pragma unroll
                for (int nt = 0; nt < 2; ++nt)
                    #pragma unroll
                    for (int j = 0; j < 4; ++j) {
                        const int m = Rb0 + 16 * mi + 4 * l4 + j;
                        const int b = m >> 2, i3 = m & 3;
                        const int n = 16 * nt + l15;
                        w4A[b][i3 * 32 + n] = f2bf(fmaxf(c3[mi][nt][j], 0.0f));
                    }
        }
        __syncthreads();   // P5e

        // ================= P6: scores + h update + publish =================
        {
            const int nt0 = 2 * oth;
            u16x8 A4[4];
            #pragma unroll
            for (int kk = 0; kk < 4; ++kk)
                A4[kk] = *(const u16x8*)&w4A[16 * mt + l15][kk * 32 + l4 * 8];
            f32x4 z4 = {0.f, 0.f, 0.f, 0.f};
            f32x4 cs[2] = {z4, z4};
            #pragma unroll
            for (int q = 0; q < 2; ++q)
                #pragma unroll
                for (int kk = 0; kk < 4; ++kk)
                    cs[q] = mfma16(A4[kk], *(const u16x8*)&W4s[16 * (nt0 + q) + l15][kk * 32 + l4 * 8], cs[q]);

            if (l < 7 && t >= 16) {   // ring back-pressure (depth 16)
                const unsigned want2 = (unsigned)(t - 15);
                while (__hip_atomic_load(&rdone[l + 1], __ATOMIC_ACQUIRE, __HIP_MEMORY_SCOPE_AGENT) < want2)
                    __builtin_amdgcn_s_sleep(2);
            }
            u16* ringout = ring + (size_t)l * 65536 + (size_t)(t & 15) * 4096;
            #pragma unroll
            for (int q = 0; q < 2; ++q) {
                const int o = 16 * (nt0 + q) + l15;
                #pragma unroll
                for (int j = 0; j < 4; ++j) {
                    const int b = 16 * mt + 4 * l4 + j;
                    float hg = h32[b][o];
                    float hn = hg * sigm(cs[q][j]);
                    h32[b][o] = hn;
                    u16 hb = f2bf(hn);
                    hbf[b][o] = hb;
                    if (l < 7) ringout[b * 64 + o] = hb;
                    else       ys[((b << 9) + t) * 64 + o] = hn;
                    if (t == 511) hfin[((l << 6) + b) * 64 + o] = hn;
                }
            }
            if (l < 7) __threadfence();
        }
        __syncthreads();   // P6e (also protects Hin/hbf/se for next iter)
        if (l < 7 && tid == 0)
            __hip_atomic_store(&wflag[l * 16 + (t & 15)], (unsigned)(t + 1),
                               __ATOMIC_RELEASE, __HIP_MEMORY_SCOPE_AGENT);
    }
}

// ---------------- heads: per-window seg + cls logits ----------------
__global__ __launch_bounds__(256) void heads_kernel(
    const float* __restrict__ ys,
    const float* __restrict__ sw1, const float* __restrict__ sb1,
    const float* __restrict__ sw2, const float* __restrict__ sb2,
    const float* __restrict__ sw3, const float* __restrict__ sb3,
    const float* __restrict__ sw4, const float* __restrict__ sb4,
    const float* __restrict__ cw1, const float* __restrict__ cb1,
    const float* __restrict__ cw2, const float* __restrict__ cb2,
    const float* __restrict__ cw3, const float* __restrict__ cb3,
    const float* __restrict__ cw4, const float* __restrict__ cb4,
    float* __restrict__ seg_out, float* __restrict__ cls_tmp)
{
    const int idx = blockIdx.x * 256 + threadIdx.x;
    if (idx >= B_ * LW) return;
    const int b = idx >> 9, t = idx & 511;

    float y[64];
    const float4* yp = (const float4*)(ys + idx * 64);
    #pragma unroll
    for (int i = 0; i < 16; ++i) {
        float4 v = yp[i];
        y[4 * i + 0] = v.x; y[4 * i + 1] = v.y; y[4 * i + 2] = v.z; y[4 * i + 3] = v.w;
    }

    float t1[8][4], t2[8][4], t3[8][4];

    // ======== seg head ========
    #pragma unroll
    for (int g = 0; g < 8; ++g)
        #pragma unroll
        for (int s = 0; s < 4; ++s) {
            float acc = sb1[s];
            #pragma unroll
            for (int k = 0; k < 8; ++k) acc = fmaf(y[g * 8 + k], sw1[s * 8 + k], acc);
            t1[g][s] = acc;
        }
    #pragma unroll
    for (int i = 0; i < 8; ++i) {
        float sh[4];
        #pragma unroll
        for (int j = 0; j < 4; ++j) { int m = i * 4 + j; sh[j] = t1[m & 7][m >> 3]; }
        #pragma unroll
        for (int s = 0; s < 4; ++s) {
            float acc = sb2[s];
            #pragma unroll
            for (int j = 0; j < 4; ++j) acc = fmaf(sh[j], sw2[s * 4 + j], acc);
            t2[i][s] = acc;
        }
    }
    #pragma unroll
    for (int i = 0; i < 8; ++i) {
        float sh[4];
        #pragma unroll
        for (int j = 0; j < 4; ++j) { int m = i * 4 + j; sh[j] = t2[m & 7][m >> 3]; }
        #pragma unroll
        for (int s = 0; s < 4; ++s) {
            float acc = sb3[s];
            #pragma unroll
            for (int j = 0; j < 4; ++j) acc = fmaf(sh[j], sw3[s * 4 + j], acc);
            t3[i][s] = acc;
        }
    }
    #pragma unroll
    for (int w = 0; w < 16; ++w) {
        float o4[4];
        #pragma unroll
        for (int s = 0; s < 4; ++s) {
            float acc = sb4[w];
            #pragma unroll
            for (int j = 0; j < 8; ++j) {
                int f = s * 8 + j;
                acc = fmaf(t3[f >> 2][f & 3], sw4[w * 8 + j], acc);
            }
            o4[s] = acc;
        }
        float4 vv = {o4[0], o4[1], o4[2], o4[3]};
        ((float4*)seg_out)[b * 8192 + t * 16 + w] = vv;
    }

    // ======== cls head ========
    #pragma unroll
    for (int g = 0; g < 8; ++g)
        #pragma unroll
        for (int s = 0; s < 4; ++s) {
            float acc = cb1[s];
            #pragma unroll
            for (int k = 0; k < 8; ++k) acc = fmaf(y[g * 8 + k], cw1[s * 8 + k], acc);
            t1[g][s] = acc;
        }
    #pragma unroll
    for (int i = 0; i < 8; ++i) {
        float sh[4];
        #pragma unroll
        for (int j = 0; j < 4; ++j) { int m = i * 4 + j; sh[j] = t1[m & 7][m >> 3]; }
        #pragma unroll
        for (int s = 0; s < 4; ++s) {
            float acc = cb2[s];
            #pragma unroll
            for (int j = 0; j < 4; ++j) acc = fmaf(sh[j], cw2[s * 4 + j], acc);
            t2[i][s] = acc;
        }
    }
    #pragma unroll
    for (int i = 0; i < 8; ++i) {
        float sh[4];
        #pragma unroll
        for (int j = 0; j < 4; ++j) { int m = i * 4 + j; sh[j] = t2[m & 7][m >> 3]; }
        #pragma unroll
        for (int s = 0; s < 4; ++s) {
            float acc = cb3[s];
            #pragma unroll
            for (int j = 0; j < 4; ++j) acc = fmaf(sh[j], cw3[s * 4 + j], acc);
            t3[i][s] = fmaxf(acc, 0.f);
        }
    }
    float cc[4];
    #pragma unroll
    for (int c = 0; c < 4; ++c) {
        float acc = cb4[c];
        #pragma unroll
        for (int k = 0; k < 32; ++k)
            acc = fmaf(t3[k >> 2][k & 3], cw4[c * 32 + k], acc);
        cc[c] = acc;
    }
    float4 cv = {cc[0], cc[1], cc[2], cc[3]};
    ((float4*)cls_tmp)[idx] = cv;
}

// ---------------- cls mean over windows ----------------
__global__ __launch_bounds__(256) void cls_reduce_kernel(
    const float* __restrict__ cls_tmp, float* __restrict__ cls_out)
{
    const int tid = threadIdx.x;
    const int b = tid >> 2, q = tid & 3;
    float ax = 0.f, ay = 0.f, az = 0.f, aw = 0.f;
    for (int t = q; t < 512; t += 4) {
        float4 v = ((const float4*)cls_tmp)[b * 512 + t];
        ax += v.x; ay += v.y; az += v.z; aw += v.w;
    }
    ax += __shfl_xor(ax, 1); ay += __shfl_xor(ay, 1);
    az += __shfl_xor(az, 1); aw += __shfl_xor(aw, 1);
    ax += __shfl_xor(ax, 2); ay += __shfl_xor(ay, 2);
    az += __shfl_xor(az, 2); aw += __shfl_xor(aw, 2);
    if (q == 0) {
        float4 rv = {ax / 512.f, ay / 512.f, az / 512.f, aw / 512.f};
        ((float4*)cls_out)[b] = rv;
    }
}

// ---------------- avg_pool1d(k=11,s=1) with 10 zero history ----------------
__global__ __launch_bounds__(256) void pool_kernel(
    const float* __restrict__ seg, float* __restrict__ pool_out)
{
    const int idx = blockIdx.x * 256 + threadIdx.x;
    if (idx >= B_ * 8192) return;
    const int b = idx >> 13, ll = idx & 8191;
    float ax = 0.f, ay = 0.f, az = 0.f, aw = 0.f;
    int j0 = ll - 10; if (j0 < 0) j0 = 0;
    for (int j = j0; j <= ll; ++j) {
        float4 v = ((const float4*)seg)[b * 8192 + j];
        ax += v.x; ay += v.y; az += v.z; aw += v.w;
    }
    const float inv = 1.0f / 11.0f;
    float4 ov = {ax * inv, ay * inv, az * inv, aw * inv};
    ((float4*)pool_out)[idx] = ov;
}

extern "C" void kernel_launch(void* const* d_in, const int* in_sizes, int n_in,
                              void* d_out, int out_size, void* d_ws, size_t ws_size,
                              hipStream_t stream)
{
    const float* x    = (const float*)d_in[0];
    const float* h0   = (const float*)d_in[1];
    const float* w_ih = (const float*)d_in[2];
    const float* w_hh = (const float*)d_in[3];
    const float* bihp = (const float*)d_in[4];
    const float* bhhp = (const float*)d_in[5];
    const float* aw1  = (const float*)d_in[6];
    const float* aw2  = (const float*)d_in[7];
    const float* aw3  = (const float*)d_in[8];
    const float* aw4  = (const float*)d_in[9];
    const float* sw1  = (const float*)d_in[10];
    const float* sb1  = (const float*)d_in[11];
    const float* sw2  = (const float*)d_in[12];
    const float* sb2  = (const float*)d_in[13];
    const float* sw3  = (const float*)d_in[14];
    const float* sb3  = (const float*)d_in[15];
    const float* sw4  = (const float*)d_in[16];
    const float* sb4  = (const float*)d_in[17];
    const float* cw1  = (const float*)d_in[18];
    const float* cb1  = (const float*)d_in[19];
    const float* cw2  = (const float*)d_in[20];
    const float* cb2  = (const float*)d_in[21];
    const float* cw3  = (const float*)d_in[22];
    const float* cb3  = (const float*)d_in[23];
    const float* cw4  = (const float*)d_in[24];
    const float* cb4  = (const float*)d_in[25];

    float* out      = (float*)d_out;
    float* pool_out = out;                 // (64,8192,4)
    float* cls_out  = out + 2097152;       // (64,4)
    float* ys_out   = out + 2097408;       // (64,512,64)
    float* hfin     = out + 4194560;       // (8,64,64)
    float* seg_out  = out + 4227328;       // (64,8192,4)
    float* cls_tmp  = pool_out;            // staged in pool region, overwritten last

    unsigned* flags = (unsigned*)d_ws;                  // 1024 B header
    u16*      ring  = (u16*)((char*)d_ws + 1024);       // 7 x 16 x 4096 bf16

    init_flags<<<1, 256, 0, stream>>>(flags);
    rnn_kernel<<<8, 512, 0, stream>>>(x, h0, w_ih, w_hh, bihp, bhhp,
                                      aw1, aw2, aw3, aw4, ys_out, hfin, flags, ring);
    heads_kernel<<<128, 256, 0, stream>>>(ys_out, sw1, sb1, sw2, sb2, sw3, sb3, sw4, sb4,
                                          cw1, cb1, cw2, cb2, cw3, cb3, cw4, cb4,
                                          seg_out, cls_tmp);
    cls_reduce_kernel<<<1, 256, 0, stream>>>(cls_tmp, cls_out);
    pool_kernel<<<2048, 256, 0, stream>>>(seg_out, pool_out);
}

// Round 3
// 4831.237 us; speedup vs baseline: 1.7053x; 1.4439x over previous
//
#include <hip/hip_runtime.h>
#include <math.h>

#define LW  512

typedef unsigned short u16;
typedef float f32x4 __attribute__((ext_vector_type(4)));
typedef u16 u16x4 __attribute__((ext_vector_type(4)));
typedef u16 u16x8 __attribute__((ext_vector_type(8)));
typedef unsigned u32x2v __attribute__((ext_vector_type(2)));
typedef __bf16 bf16x8 __attribute__((ext_vector_type(8)));

__device__ __forceinline__ u16 f2bf(float f) {
    unsigned u = __builtin_bit_cast(unsigned, f);
    unsigned r = (u + 0x7fffu + ((u >> 16) & 1u)) >> 16;
    return (u16)r;
}
__device__ __forceinline__ float bf2f(u16 h) {
    unsigned u = ((unsigned)h) << 16;
    return __builtin_bit_cast(float, u);
}
__device__ __forceinline__ float sigm(float x) {
    return __builtin_amdgcn_rcpf(1.0f + __expf(-x));
}
__device__ __forceinline__ float tanhfast(float x) {
    return 1.0f - 2.0f * __builtin_amdgcn_rcpf(1.0f + __expf(2.0f * x));
}
__device__ __forceinline__ f32x4 mfma16(u16x8 a, u16x8 b, f32x4 c) {
    return __builtin_amdgcn_mfma_f32_16x16x32_bf16(
        __builtin_bit_cast(bf16x8, a), __builtin_bit_cast(bf16x8, b), c, 0, 0, 0);
}
__device__ __forceinline__ u16x8 ld8_8al(const u16* p) {   // 8B-aligned 16B load
    u16x4 lo = *(const u16x4*)p;
    u16x4 hi = *(const u16x4*)(p + 4);
    return __builtin_shufflevector(lo, hi, 0, 1, 2, 3, 4, 5, 6, 7);
}

// flags: wflag[7][8][16] (=896) + rdone[8][8] (=64) -> 1024 u32
__global__ __launch_bounds__(256) void init_flags(unsigned* f) {
    int i = blockIdx.x * 256 + threadIdx.x;
    if (i < 1024) f[i] = 0u;
}

// ---------------- recurrence: (layer, batch-group) per block ----------------
// grid = 64 (block = l*8+g), block = 256 (4 waves). 8 batches per block.
// All weight B-fragments live in VGPRs; LDS holds only activations (~16KB).
__global__ __launch_bounds__(256, 1) void rnn_kernel(
    const float* __restrict__ x, const float* __restrict__ h0,
    const float* __restrict__ w_ih, const float* __restrict__ w_hh,
    const float* __restrict__ bih, const float* __restrict__ bhh,
    const float* __restrict__ aw1, const float* __restrict__ aw2,
    const float* __restrict__ aw3, const float* __restrict__ aw4,
    float* __restrict__ ys, float* __restrict__ hfin,
    unsigned* __restrict__ flags, u16* __restrict__ ring)
{
    const int l   = blockIdx.x >> 3;   // layer 0..7
    const int g   = blockIdx.x & 7;    // batch group 0..7
    const int bb0 = g * 8;             // first batch of this group
    const int tid = threadIdx.x;
    const int w   = tid >> 6;          // wave 0..3
    const int ln  = tid & 63;
    const int l15 = ln & 15;
    const int l4  = ln >> 4;

    unsigned* wflag = flags;           // [7][8][16]
    unsigned* rdone = flags + 896;     // [8][8]

    __shared__ __align__(16) u16 Hin[16][72];   // layer input (bf16), rows 8..15 zero
    __shared__ __align__(16) u16 hbf[16][72];   // h state (bf16),   rows 8..15 zero
    __shared__ __align__(16) u16 se [16][72];   // rows 0..7 = h, 8..15 = sorted h
    __shared__ __align__(16) u16 a23[32][36];   // a1-shuffled / a2-shuffled overlay
    __shared__ __align__(16) u16 w4A[16][136];  // relu(a3) flat 128, rows 8..15 zero

    // ---- zero pad rows (read by MFMA A-operands, never written later) ----
    for (int i = tid; i < 16 * 72; i += 256) {
        int r = i / 72, c = i % 72;
        if (r >= 8) { Hin[r][c] = 0; hbf[r][c] = 0; }
    }
    for (int i = tid; i < 16 * 136; i += 256) {
        int r = i / 136;
        if (r >= 8) w4A[r][i % 136] = 0;
    }

    // ---- hoist all weight B-fragments into VGPRs (t-invariant) ----
    const int o = 16 * w + l15;   // this wave's output column (GRU / a1 / W4 N-tile)
    auto ldw8 = [](const float* p) {
        float4 v0 = *(const float4*)p;
        float4 v1 = *(const float4*)(p + 4);
        u16x8 r;
        r[0] = f2bf(v0.x); r[1] = f2bf(v0.y); r[2] = f2bf(v0.z); r[3] = f2bf(v0.w);
        r[4] = f2bf(v1.x); r[5] = f2bf(v1.y); r[6] = f2bf(v1.z); r[7] = f2bf(v1.w);
        return r;
    };
    const float* ih = w_ih + l * 12288;
    const float* hh = w_hh + l * 12288;
    u16x8 Br[4], Bz[4], Bni[2], Bnh[2], B1f[2], B2f[2], B3f[2], B4f[4];
    Br[0] = ldw8(ih + o * 64 + l4 * 8);        Br[1] = ldw8(ih + o * 64 + 32 + l4 * 8);
    Br[2] = ldw8(hh + o * 64 + l4 * 8);        Br[3] = ldw8(hh + o * 64 + 32 + l4 * 8);
    Bz[0] = ldw8(ih + (64 + o) * 64 + l4 * 8); Bz[1] = ldw8(ih + (64 + o) * 64 + 32 + l4 * 8);
    Bz[2] = ldw8(hh + (64 + o) * 64 + l4 * 8); Bz[3] = ldw8(hh + (64 + o) * 64 + 32 + l4 * 8);
    Bni[0] = ldw8(ih + (128 + o) * 64 + l4 * 8); Bni[1] = ldw8(ih + (128 + o) * 64 + 32 + l4 * 8);
    Bnh[0] = ldw8(hh + (128 + o) * 64 + l4 * 8); Bnh[1] = ldw8(hh + (128 + o) * 64 + 32 + l4 * 8);
    B1f[0] = ldw8(aw1 + l * 4096 + o * 64 + l4 * 8);
    B1f[1] = ldw8(aw1 + l * 4096 + o * 64 + 32 + l4 * 8);
    B2f[0] = ldw8(aw2 + l * 1024 + l15 * 32 + l4 * 8);
    B2f[1] = ldw8(aw2 + l * 1024 + (16 + l15) * 32 + l4 * 8);
    B3f[0] = ldw8(aw3 + l * 1024 + l15 * 32 + l4 * 8);
    B3f[1] = ldw8(aw3 + l * 1024 + (16 + l15) * 32 + l4 * 8);
    #pragma unroll
    for (int kk = 0; kk < 4; ++kk)
        B4f[kk] = ldw8(aw4 + l * 8192 + o * 128 + kk * 32 + l4 * 8);

    const float brs  = bih[l * 192 + o]       + bhh[l * 192 + o];
    const float bzs  = bih[l * 192 + 64 + o]  + bhh[l * 192 + 64 + o];
    const float bnis = bih[l * 192 + 128 + o];
    const float bnhs = bhh[l * 192 + 128 + o];

    // f32 h-state fully in registers: lane (l4<2, j) owns (row=l4*4+j, col=o)
    float hreg[4];
    {
        float hv = h0[l * 64 + o];
        #pragma unroll
        for (int j = 0; j < 4; ++j) hreg[j] = hv;
        if (l4 < 2) {
            u16 hb = f2bf(hv);
            #pragma unroll
            for (int j = 0; j < 4; ++j) hbf[l4 * 4 + j][o] = hb;
        }
    }
    __syncthreads();

    for (int t = 0; t < LW; ++t) {
        float hg[4];
        // ================= P0: acquire input =================
        if (l == 0) {
            if (tid < 128) {
                int r = tid >> 4, c4 = (tid & 15) * 4;
                const float4 v = *(const float4*)(x + (size_t)(bb0 + r) * 32768 + t * 64 + c4);
                u16x4 hv;
                hv[0] = f2bf(v.x); hv[1] = f2bf(v.y); hv[2] = f2bf(v.z); hv[3] = f2bf(v.w);
                *(u16x4*)&Hin[r][c4] = hv;
            }
        } else {
            const unsigned want = (unsigned)(t + 1);
            while (__hip_atomic_load(&wflag[((l - 1) * 8 + g) * 16 + (t & 15)],
                                     __ATOMIC_ACQUIRE, __HIP_MEMORY_SCOPE_AGENT) < want)
                __builtin_amdgcn_s_sleep(1);
            if (tid < 128) {
                int r = tid >> 4, c4 = (tid & 15) * 4;
                const unsigned* src =
                    (const unsigned*)(ring + ((size_t)((l - 1) * 8 + g) * 16 + (t & 15)) * 512)
                    + ((r * 64 + c4) >> 1);
                unsigned d0 = __hip_atomic_load(src + 0, __ATOMIC_RELAXED, __HIP_MEMORY_SCOPE_AGENT);
                unsigned d1 = __hip_atomic_load(src + 1, __ATOMIC_RELAXED, __HIP_MEMORY_SCOPE_AGENT);
                u32x2v dv = {d0, d1};
                *(u16x4*)&Hin[r][c4] = __builtin_bit_cast(u16x4, dv);
            }
        }
        __syncthreads();   // P0e
        if (l > 0 && tid == 0)
            __hip_atomic_store(&rdone[l * 8 + g], (unsigned)(t + 1),
                               __ATOMIC_RELEASE, __HIP_MEMORY_SCOPE_AGENT);

        // ================= P1: GRU =================
        {
            u16x8 Ag0 = *(const u16x8*)&Hin[l15][l4 * 8];
            u16x8 Ag1 = *(const u16x8*)&Hin[l15][32 + l4 * 8];
            u16x8 Ah0 = *(const u16x8*)&hbf[l15][l4 * 8];
            u16x8 Ah1 = *(const u16x8*)&hbf[l15][32 + l4 * 8];
            f32x4 z4 = {0.f, 0.f, 0.f, 0.f};
            f32x4 aR = z4, aZ = z4, aNI = z4, aNH = z4;
            aR = mfma16(Ag0, Br[0], aR);  aR = mfma16(Ag1, Br[1], aR);
            aR = mfma16(Ah0, Br[2], aR);  aR = mfma16(Ah1, Br[3], aR);
            aZ = mfma16(Ag0, Bz[0], aZ);  aZ = mfma16(Ag1, Bz[1], aZ);
            aZ = mfma16(Ah0, Bz[2], aZ);  aZ = mfma16(Ah1, Bz[3], aZ);
            aNI = mfma16(Ag0, Bni[0], aNI); aNI = mfma16(Ag1, Bni[1], aNI);
            aNH = mfma16(Ah0, Bnh[0], aNH); aNH = mfma16(Ah1, Bnh[1], aNH);
            #pragma unroll
            for (int j = 0; j < 4; ++j) {
                float r  = sigm(aR[j] + brs);
                float zz = sigm(aZ[j] + bzs);
                float nn = tanhfast(aNI[j] + bnis + r * (aNH[j] + bnhs));
                hg[j] = (1.0f - zz) * nn + zz * hreg[j];
            }
            if (l4 < 2) {
                #pragma unroll
                for (int j = 0; j < 4; ++j) se[l4 * 4 + j][o] = f2bf(hg[j]);
            }
        }
        __syncthreads();   // P1e

        // ================= P2: bitonic sort (2 rows per wave) =================
        {
            float v0 = bf2f(se[2 * w][ln]);
            float v1 = bf2f(se[2 * w + 1][ln]);
            #pragma unroll
            for (int kk = 2; kk <= 64; kk <<= 1) {
                #pragma unroll
                for (int j = kk >> 1; j > 0; j >>= 1) {
                    float o0 = __shfl_xor(v0, j);
                    float o1 = __shfl_xor(v1, j);
                    bool keepmin = (((ln & kk) == 0) == ((ln & j) == 0));
                    v0 = keepmin ? fminf(v0, o0) : fmaxf(v0, o0);
                    v1 = keepmin ? fminf(v1, o1) : fmaxf(v1, o1);
                }
            }
            se[8 + 2 * w][ln] = f2bf(v0);
            se[9 + 2 * w][ln] = f2bf(v1);
        }
        __syncthreads();   // P2e

        // ================= P3: a1 = se @ W1^T, shuffle-write =================
        {
            u16x8 As0 = *(const u16x8*)&se[l15][l4 * 8];
            u16x8 As1 = *(const u16x8*)&se[l15][32 + l4 * 8];
            f32x4 c = {0.f, 0.f, 0.f, 0.f};
            c = mfma16(As0, B1f[0], c);
            c = mfma16(As1, B1f[1], c);
            #pragma unroll
            for (int j = 0; j < 4; ++j) {
                int m = l4 * 4 + j;            // 0..15: p = m>>3 (se half), b = m&7
                int p = m >> 3, b = m & 7;
                int f = p * 64 + o;
                int q = (f & 31) * 4 + (f >> 5);
                a23[b * 4 + (q >> 5)][q & 31] = f2bf(c[j]);
            }
        }
        __syncthreads();   // P3e

        // ================= P4/P5: a2 then a3 (waves 0,1 only) =================
        if (w < 2) {
            const int Rb0 = 16 * w;
            u16x8 a2a = ld8_8al(&a23[Rb0 + l15][l4 * 8]);
            f32x4 z4 = {0.f, 0.f, 0.f, 0.f};
            f32x4 c2[2];
            c2[0] = mfma16(a2a, B2f[0], z4);
            c2[1] = mfma16(a2a, B2f[1], z4);
            #pragma unroll
            for (int nt = 0; nt < 2; ++nt)
                #pragma unroll
                for (int j = 0; j < 4; ++j) {
                    int m = Rb0 + l4 * 4 + j;
                    int b = m >> 2, i2 = m & 3;
                    int n = 16 * nt + l15;
                    int f2 = i2 * 32 + n;
                    int q2 = (f2 & 31) * 4 + (f2 >> 5);
                    a23[b * 4 + (q2 >> 5)][q2 & 31] = f2bf(c2[nt][j]);
                }
            asm volatile("s_waitcnt lgkmcnt(0)" ::: "memory");
            __builtin_amdgcn_sched_barrier(0);
            u16x8 a3a = ld8_8al(&a23[Rb0 + l15][l4 * 8]);
            f32x4 c3[2];
            c3[0] = mfma16(a3a, B3f[0], z4);
            c3[1] = mfma16(a3a, B3f[1], z4);
            #pragma unroll
            for (int nt = 0; nt < 2; ++nt)
                #pragma unroll
                for (int j = 0; j < 4; ++j) {
                    int m = Rb0 + l4 * 4 + j;
                    int b = m >> 2, i3 = m & 3;
                    int n = 16 * nt + l15;
                    w4A[b][i3 * 32 + n] = f2bf(fmaxf(c3[nt][j], 0.0f));
                }
        }
        __syncthreads();   // P5e

        // ================= P6: scores + h update + publish =================
        {
            u16x8 A40 = *(const u16x8*)&w4A[l15][l4 * 8];
            u16x8 A41 = *(const u16x8*)&w4A[l15][32 + l4 * 8];
            u16x8 A42 = *(const u16x8*)&w4A[l15][64 + l4 * 8];
            u16x8 A43 = *(const u16x8*)&w4A[l15][96 + l4 * 8];
            f32x4 cs = {0.f, 0.f, 0.f, 0.f};
            cs = mfma16(A40, B4f[0], cs);
            cs = mfma16(A41, B4f[1], cs);
            cs = mfma16(A42, B4f[2], cs);
            cs = mfma16(A43, B4f[3], cs);

            if (l < 7 && t >= 16) {   // ring back-pressure (depth 16)
                const unsigned want2 = (unsigned)(t - 15);
                while (__hip_atomic_load(&rdone[(l + 1) * 8 + g],
                                         __ATOMIC_ACQUIRE, __HIP_MEMORY_SCOPE_AGENT) < want2)
                    __builtin_amdgcn_s_sleep(1);
            }
            u16* ringout = ring + ((size_t)(l * 8 + g) * 16 + (t & 15)) * 512;
            #pragma unroll
            for (int j = 0; j < 4; ++j) {
                float hn = hg[j] * sigm(cs[j]);
                hreg[j] = hn;
                if (l4 < 2) {
                    int row = l4 * 4 + j;
                    u16 hb = f2bf(hn);
                    hbf[row][o] = hb;
                    if (l < 7) ringout[row * 64 + o] = hb;
                    else       ys[(((size_t)(bb0 + row) << 9) + t) * 64 + o] = hn;
                    if (t == 511) hfin[((l << 6) + bb0 + row) * 64 + o] = hn;
                }
            }
            if (l < 7) __threadfence();
        }
        __syncthreads();   // P6e
        if (l < 7 && tid == 0)
            __hip_atomic_store(&wflag[(l * 8 + g) * 16 + (t & 15)], (unsigned)(t + 1),
                               __ATOMIC_RELEASE, __HIP_MEMORY_SCOPE_AGENT);
    }
}

// ---------------- heads: per-window seg + cls logits ----------------
__global__ __launch_bounds__(256) void heads_kernel(
    const float* __restrict__ ys,
    const float* __restrict__ sw1, const float* __restrict__ sb1,
    const float* __restrict__ sw2, const float* __restrict__ sb2,
    const float* __restrict__ sw3, const float* __restrict__ sb3,
    const float* __restrict__ sw4, const float* __restrict__ sb4,
    const float* __restrict__ cw1, const float* __restrict__ cb1,
    const float* __restrict__ cw2, const float* __restrict__ cb2,
    const float* __restrict__ cw3, const float* __restrict__ cb3,
    const float* __restrict__ cw4, const float* __restrict__ cb4,
    float* __restrict__ seg_out, float* __restrict__ cls_tmp)
{
    const int idx = blockIdx.x * 256 + threadIdx.x;
    if (idx >= 64 * LW) return;
    const int b = idx >> 9, t = idx & 511;

    float y[64];
    const float4* yp = (const float4*)(ys + (size_t)idx * 64);
    #pragma unroll
    for (int i = 0; i < 16; ++i) {
        float4 v = yp[i];
        y[4 * i + 0] = v.x; y[4 * i + 1] = v.y; y[4 * i + 2] = v.z; y[4 * i + 3] = v.w;
    }

    float t1[8][4], t2[8][4], t3[8][4];

    // ======== seg head ========
    #pragma unroll
    for (int g = 0; g < 8; ++g)
        #pragma unroll
        for (int s = 0; s < 4; ++s) {
            float acc = sb1[s];
            #pragma unroll
            for (int k = 0; k < 8; ++k) acc = fmaf(y[g * 8 + k], sw1[s * 8 + k], acc);
            t1[g][s] = acc;
        }
    #pragma unroll
    for (int i = 0; i < 8; ++i) {
        float sh[4];
        #pragma unroll
        for (int j = 0; j < 4; ++j) { int m = i * 4 + j; sh[j] = t1[m & 7][m >> 3]; }
        #pragma unroll
        for (int s = 0; s < 4; ++s) {
            float acc = sb2[s];
            #pragma unroll
            for (int j = 0; j < 4; ++j) acc = fmaf(sh[j], sw2[s * 4 + j], acc);
            t2[i][s] = acc;
        }
    }
    #pragma unroll
    for (int i = 0; i < 8; ++i) {
        float sh[4];
        #pragma unroll
        for (int j = 0; j < 4; ++j) { int m = i * 4 + j; sh[j] = t2[m & 7][m >> 3]; }
        #pragma unroll
        for (int s = 0; s < 4; ++s) {
            float acc = sb3[s];
            #pragma unroll
            for (int j = 0; j < 4; ++j) acc = fmaf(sh[j], sw3[s * 4 + j], acc);
            t3[i][s] = acc;
        }
    }
    #pragma unroll
    for (int w = 0; w < 16; ++w) {
        float o4[4];
        #pragma unroll
        for (int s = 0; s < 4; ++s) {
            float acc = sb4[w];
            #pragma unroll
            for (int j = 0; j < 8; ++j) {
                int f = s * 8 + j;
                acc = fmaf(t3[f >> 2][f & 3], sw4[w * 8 + j], acc);
            }
            o4[s] = acc;
        }
        float4 vv = {o4[0], o4[1], o4[2], o4[3]};
        ((float4*)seg_out)[b * 8192 + t * 16 + w] = vv;
    }

    // ======== cls head ========
    #pragma unroll
    for (int g = 0; g < 8; ++g)
        #pragma unroll
        for (int s = 0; s < 4; ++s) {
            float acc = cb1[s];
            #pragma unroll
            for (int k = 0; k < 8; ++k) acc = fmaf(y[g * 8 + k], cw1[s * 8 + k], acc);
            t1[g][s] = acc;
        }
    #pragma unroll
    for (int i = 0; i < 8; ++i) {
        float sh[4];
        #pragma unroll
        for (int j = 0; j < 4; ++j) { int m = i * 4 + j; sh[j] = t1[m & 7][m >> 3]; }
        #pragma unroll
        for (int s = 0; s < 4; ++s) {
            float acc = cb2[s];
            #pragma unroll
            for (int j = 0; j < 4; ++j) acc = fmaf(sh[j], cw2[s * 4 + j], acc);
            t2[i][s] = acc;
        }
    }
    #pragma unroll
    for (int i = 0; i < 8; ++i) {
        float sh[4];
        #pragma unroll
        for (int j = 0; j < 4; ++j) { int m = i * 4 + j; sh[j] = t2[m & 7][m >> 3]; }
        #pragma unroll
        for (int s = 0; s < 4; ++s) {
            float acc = cb3[s];
            #pragma unroll
            for (int j = 0; j < 4; ++j) acc = fmaf(sh[j], cw3[s * 4 + j], acc);
            t3[i][s] = fmaxf(acc, 0.f);
        }
    }
    float cc[4];
    #pragma unroll
    for (int c = 0; c < 4; ++c) {
        float acc = cb4[c];
        #pragma unroll
        for (int k = 0; k < 32; ++k)
            acc = fmaf(t3[k >> 2][k & 3], cw4[c * 32 + k], acc);
        cc[c] = acc;
    }
    float4 cv = {cc[0], cc[1], cc[2], cc[3]};
    ((float4*)cls_tmp)[idx] = cv;
}

// ---------------- cls mean over windows ----------------
__global__ __launch_bounds__(256) void cls_reduce_kernel(
    const float* __restrict__ cls_tmp, float* __restrict__ cls_out)
{
    const int tid = threadIdx.x;
    const int b = tid >> 2, q = tid & 3;
    float ax = 0.f, ay = 0.f, az = 0.f, aw = 0.f;
    for (int t = q; t < 512; t += 4) {
        float4 v = ((const float4*)cls_tmp)[b * 512 + t];
        ax += v.x; ay += v.y; az += v.z; aw += v.w;
    }
    ax += __shfl_xor(ax, 1); ay += __shfl_xor(ay, 1);
    az += __shfl_xor(az, 1); aw += __shfl_xor(aw, 1);
    ax += __shfl_xor(ax, 2); ay += __shfl_xor(ay, 2);
    az += __shfl_xor(az, 2); aw += __shfl_xor(aw, 2);
    if (q == 0) {
        float4 rv = {ax / 512.f, ay / 512.f, az / 512.f, aw / 512.f};
        ((float4*)cls_out)[b] = rv;
    }
}

// ---------------- avg_pool1d(k=11,s=1) with 10 zero history ----------------
__global__ __launch_bounds__(256) void pool_kernel(
    const float* __restrict__ seg, float* __restrict__ pool_out)
{
    const int idx = blockIdx.x * 256 + threadIdx.x;
    if (idx >= 64 * 8192) return;
    const int b = idx >> 13, ll = idx & 8191;
    float ax = 0.f, ay = 0.f, az = 0.f, aw = 0.f;
    int j0 = ll - 10; if (j0 < 0) j0 = 0;
    for (int j = j0; j <= ll; ++j) {
        float4 v = ((const float4*)seg)[b * 8192 + j];
        ax += v.x; ay += v.y; az += v.z; aw += v.w;
    }
    const float inv = 1.0f / 11.0f;
    float4 ov = {ax * inv, ay * inv, az * inv, aw * inv};
    ((float4*)pool_out)[idx] = ov;
}

extern "C" void kernel_launch(void* const* d_in, const int* in_sizes, int n_in,
                              void* d_out, int out_size, void* d_ws, size_t ws_size,
                              hipStream_t stream)
{
    const float* x    = (const float*)d_in[0];
    const float* h0   = (const float*)d_in[1];
    const float* w_ih = (const float*)d_in[2];
    const float* w_hh = (const float*)d_in[3];
    const float* bihp = (const float*)d_in[4];
    const float* bhhp = (const float*)d_in[5];
    const float* aw1  = (const float*)d_in[6];
    const float* aw2  = (const float*)d_in[7];
    const float* aw3  = (const float*)d_in[8];
    const float* aw4  = (const float*)d_in[9];
    const float* sw1  = (const float*)d_in[10];
    const float* sb1  = (const float*)d_in[11];
    const float* sw2  = (const float*)d_in[12];
    const float* sb2  = (const float*)d_in[13];
    const float* sw3  = (const float*)d_in[14];
    const float* sb3  = (const float*)d_in[15];
    const float* sw4  = (const float*)d_in[16];
    const float* sb4  = (const float*)d_in[17];
    const float* cw1  = (const float*)d_in[18];
    const float* cb1  = (const float*)d_in[19];
    const float* cw2  = (const float*)d_in[20];
    const float* cb2  = (const float*)d_in[21];
    const float* cw3  = (const float*)d_in[22];
    const float* cb3  = (const float*)d_in[23];
    const float* cw4  = (const float*)d_in[24];
    const float* cb4  = (const float*)d_in[25];

    float* out      = (float*)d_out;
    float* pool_out = out;                 // (64,8192,4)
    float* cls_out  = out + 2097152;       // (64,4)
    float* ys_out   = out + 2097408;       // (64,512,64)
    float* hfin     = out + 4194560;       // (8,64,64)
    float* seg_out  = out + 4227328;       // (64,8192,4)
    float* cls_tmp  = pool_out;            // staged in pool region, overwritten last

    unsigned* flags = (unsigned*)d_ws;                  // 4096 B header
    u16*      ring  = (u16*)((char*)d_ws + 4096);       // 56 x 16 x 512 bf16 (~896KB)

    init_flags<<<4, 256, 0, stream>>>(flags);
    rnn_kernel<<<64, 256, 0, stream>>>(x, h0, w_ih, w_hh, bihp, bhhp,
                                       aw1, aw2, aw3, aw4, ys_out, hfin, flags, ring);
    heads_kernel<<<128, 256, 0, stream>>>(ys_out, sw1, sb1, sw2, sb2, sw3, sb3, sw4, sb4,
                                          cw1, cb1, cw2, cb2, cw3, cb3, cw4, cb4,
                                          seg_out, cls_tmp);
    cls_reduce_kernel<<<1, 256, 0, stream>>>(cls_tmp, cls_out);
    pool_kernel<<<2048, 256, 0, stream>>>(seg_out, pool_out);
}

// Round 4
// 1678.475 us; speedup vs baseline: 4.9083x; 2.8783x over previous
//
#include <hip/hip_runtime.h>
#include <math.h>

#define LW  512

typedef unsigned short u16;
typedef float f32x4 __attribute__((ext_vector_type(4)));
typedef u16 u16x4 __attribute__((ext_vector_type(4)));
typedef u16 u16x8 __attribute__((ext_vector_type(8)));
typedef unsigned u32x2v __attribute__((ext_vector_type(2)));
typedef __bf16 bf16x8 __attribute__((ext_vector_type(8)));

__device__ __forceinline__ u16 f2bf(float f) {
    unsigned u = __builtin_bit_cast(unsigned, f);
    unsigned r = (u + 0x7fffu + ((u >> 16) & 1u)) >> 16;
    return (u16)r;
}
__device__ __forceinline__ float bf2f(u16 h) {
    unsigned u = ((unsigned)h) << 16;
    return __builtin_bit_cast(float, u);
}
__device__ __forceinline__ float sigm(float x) {
    return __builtin_amdgcn_rcpf(1.0f + __expf(-x));
}
__device__ __forceinline__ float tanhfast(float x) {
    return 1.0f - 2.0f * __builtin_amdgcn_rcpf(1.0f + __expf(2.0f * x));
}
__device__ __forceinline__ f32x4 mfma16(u16x8 a, u16x8 b, f32x4 c) {
    return __builtin_amdgcn_mfma_f32_16x16x32_bf16(
        __builtin_bit_cast(bf16x8, a), __builtin_bit_cast(bf16x8, b), c, 0, 0, 0);
}
__device__ __forceinline__ u16x8 ld8_8al(const u16* p) {   // 8B-aligned 16B load
    u16x4 lo = *(const u16x4*)p;
    u16x4 hi = *(const u16x4*)(p + 4);
    return __builtin_shufflevector(lo, hi, 0, 1, 2, 3, 4, 5, 6, 7);
}
__device__ __forceinline__ unsigned ld_sys(const unsigned* p) {
    return __hip_atomic_load(p, __ATOMIC_RELAXED, __HIP_MEMORY_SCOPE_SYSTEM);
}
__device__ __forceinline__ void st_sys(unsigned* p, unsigned v) {
    __hip_atomic_store(p, v, __ATOMIC_RELAXED, __HIP_MEMORY_SCOPE_SYSTEM);
}
__device__ __forceinline__ void poll_ge(const unsigned* p, unsigned want) {
    while (ld_sys(p) < want) __builtin_amdgcn_s_sleep(2);
    asm volatile("" ::: "memory");
    __builtin_amdgcn_sched_barrier(0);
}
__device__ __forceinline__ void bar_lgkm() {
    asm volatile("s_waitcnt lgkmcnt(0)" ::: "memory");
    __builtin_amdgcn_s_barrier();
}

// zero counters: cnt[(l*8+g)*32] and ccnt at +4096 -> zero 8192 u32
__global__ __launch_bounds__(256) void init_flags(unsigned* f) {
    f[blockIdx.x * 256 + threadIdx.x] = 0u;
}

// ---------------- recurrence: (layer, batch-group) per block ----------------
// grid = 64 (block = l*8+g), block = 256 (4 waves). 8 batches per block.
// Weight B-fragments in VGPRs. Relaxed system-scope flags (no cache maintenance),
// deep ring (1 slot per timestep when ws allows), waves 2-3 prefetch next inputs
// during the attention a2/a3 phase.
__global__ __launch_bounds__(256, 1) void rnn_kernel(
    const float* __restrict__ x, const float* __restrict__ h0,
    const float* __restrict__ w_ih, const float* __restrict__ w_hh,
    const float* __restrict__ bih, const float* __restrict__ bhh,
    const float* __restrict__ aw1, const float* __restrict__ aw2,
    const float* __restrict__ aw3, const float* __restrict__ aw4,
    float* __restrict__ ys, float* __restrict__ hfin,
    unsigned* __restrict__ flags, unsigned* __restrict__ ring32, int D)
{
    const int l   = blockIdx.x >> 3;   // layer 0..7
    const int g   = blockIdx.x & 7;    // batch group 0..7
    const int bb0 = g * 8;
    const int tid = threadIdx.x;
    const int w   = tid >> 6;          // wave 0..3
    const int ln  = tid & 63;
    const int l15 = ln & 15;
    const int l4  = ln >> 4;
    const bool bp = (D < LW);          // back-pressure only for shallow ring

    unsigned* mycnt  = flags + (size_t)(l * 8 + g) * 32;
    unsigned* pcnt   = flags + (size_t)((l - 1) * 8 + g) * 32;
    unsigned* myccnt = flags + 4096 + (size_t)(l * 8 + g) * 32;
    unsigned* nccnt  = flags + 4096 + (size_t)((l + 1) * 8 + g) * 32;

    __shared__ __align__(16) u16 Hin[2][16][72]; // dbl-buffered layer input, rows 8..15 zero
    __shared__ __align__(16) u16 hbf[16][72];    // h state (bf16), rows 8..15 zero
    __shared__ __align__(16) u16 se [16][72];    // rows 0..7 = h, 8..15 = sorted h
    __shared__ __align__(16) u16 a23[32][36];    // a1-shuffled / a2-shuffled overlay
    __shared__ __align__(16) u16 w4A[16][136];   // relu(a3) flat 128, rows 8..15 zero

    for (int i = tid; i < 16 * 72; i += 256) {
        int r = i / 72, c = i % 72;
        if (r >= 8) { Hin[0][r][c] = 0; Hin[1][r][c] = 0; hbf[r][c] = 0; }
    }
    for (int i = tid; i < 16 * 136; i += 256) {
        int r = i / 136;
        if (r >= 8) w4A[r][i % 136] = 0;
    }

    // ---- weight B-fragments into VGPRs (t-invariant) ----
    const int o = 16 * w + l15;
    auto ldw8 = [](const float* p) {
        float4 v0 = *(const float4*)p;
        float4 v1 = *(const float4*)(p + 4);
        u16x8 r;
        r[0] = f2bf(v0.x); r[1] = f2bf(v0.y); r[2] = f2bf(v0.z); r[3] = f2bf(v0.w);
        r[4] = f2bf(v1.x); r[5] = f2bf(v1.y); r[6] = f2bf(v1.z); r[7] = f2bf(v1.w);
        return r;
    };
    const float* ih = w_ih + l * 12288;
    const float* hh = w_hh + l * 12288;
    u16x8 Br[4], Bz[4], Bni[2], Bnh[2], B1f[2], B2f[2], B3f[2], B4f[4];
    Br[0] = ldw8(ih + o * 64 + l4 * 8);        Br[1] = ldw8(ih + o * 64 + 32 + l4 * 8);
    Br[2] = ldw8(hh + o * 64 + l4 * 8);        Br[3] = ldw8(hh + o * 64 + 32 + l4 * 8);
    Bz[0] = ldw8(ih + (64 + o) * 64 + l4 * 8); Bz[1] = ldw8(ih + (64 + o) * 64 + 32 + l4 * 8);
    Bz[2] = ldw8(hh + (64 + o) * 64 + l4 * 8); Bz[3] = ldw8(hh + (64 + o) * 64 + 32 + l4 * 8);
    Bni[0] = ldw8(ih + (128 + o) * 64 + l4 * 8); Bni[1] = ldw8(ih + (128 + o) * 64 + 32 + l4 * 8);
    Bnh[0] = ldw8(hh + (128 + o) * 64 + l4 * 8); Bnh[1] = ldw8(hh + (128 + o) * 64 + 32 + l4 * 8);
    B1f[0] = ldw8(aw1 + l * 4096 + o * 64 + l4 * 8);
    B1f[1] = ldw8(aw1 + l * 4096 + o * 64 + 32 + l4 * 8);
    B2f[0] = ldw8(aw2 + l * 1024 + l15 * 32 + l4 * 8);
    B2f[1] = ldw8(aw2 + l * 1024 + (16 + l15) * 32 + l4 * 8);
    B3f[0] = ldw8(aw3 + l * 1024 + l15 * 32 + l4 * 8);
    B3f[1] = ldw8(aw3 + l * 1024 + (16 + l15) * 32 + l4 * 8);
    #pragma unroll
    for (int kk = 0; kk < 4; ++kk)
        B4f[kk] = ldw8(aw4 + l * 8192 + o * 128 + kk * 32 + l4 * 8);

    const float brs  = bih[l * 192 + o]       + bhh[l * 192 + o];
    const float bzs  = bih[l * 192 + 64 + o]  + bhh[l * 192 + 64 + o];
    const float bnis = bih[l * 192 + 128 + o];
    const float bnhs = bhh[l * 192 + 128 + o];

    float hreg[4];
    {
        float hv = h0[l * 64 + o];
        #pragma unroll
        for (int j = 0; j < 4; ++j) hreg[j] = hv;
        if (l4 < 2) {
            u16 hb = f2bf(hv);
            #pragma unroll
            for (int j = 0; j < 4; ++j) hbf[l4 * 4 + j][o] = hb;
        }
    }

    // ---- prologue: stage slot 0 into Hin[0]; slot 1 into stash regs ----
    float4 stf = {0.f, 0.f, 0.f, 0.f};
    unsigned st0 = 0, st1 = 0;
    if (w >= 2) {
        const int rr = (tid - 128) >> 4, c4 = ((tid - 128) & 15) * 4;
        if (l == 0) {
            float4 a = *(const float4*)(x + (size_t)(bb0 + rr) * 32768 + c4);
            u16x4 hv;
            hv[0] = f2bf(a.x); hv[1] = f2bf(a.y); hv[2] = f2bf(a.z); hv[3] = f2bf(a.w);
            *(u16x4*)&Hin[0][rr][c4] = hv;
            stf = *(const float4*)(x + (size_t)(bb0 + rr) * 32768 + 64 + c4);
        } else {
            poll_ge(pcnt, 1u);
            const unsigned* sp0 = ring32 + ((size_t)((l - 1) * 8 + g) * D + 0) * 256 + rr * 32 + (c4 >> 1);
            unsigned a0 = ld_sys(sp0), a1 = ld_sys(sp0 + 1);
            u32x2v dv = {a0, a1};
            *(u16x4*)&Hin[0][rr][c4] = __builtin_bit_cast(u16x4, dv);
            poll_ge(pcnt, 2u);
            const unsigned* sp1 = ring32 + ((size_t)((l - 1) * 8 + g) * D + 1) * 256 + rr * 32 + (c4 >> 1);
            st0 = ld_sys(sp1); st1 = ld_sys(sp1 + 1);
        }
    }
    __syncthreads();

    for (int t = 0; t < LW; ++t) {
        float hg[4];
        // ================= P1: GRU (reads Hin[t&1]) =================
        {
            u16x8 Ag0 = *(const u16x8*)&Hin[t & 1][l15][l4 * 8];
            u16x8 Ag1 = *(const u16x8*)&Hin[t & 1][l15][32 + l4 * 8];
            u16x8 Ah0 = *(const u16x8*)&hbf[l15][l4 * 8];
            u16x8 Ah1 = *(const u16x8*)&hbf[l15][32 + l4 * 8];
            f32x4 z4 = {0.f, 0.f, 0.f, 0.f};
            f32x4 aR = z4, aZ = z4, aNI = z4, aNH = z4;
            aR = mfma16(Ag0, Br[0], aR);  aR = mfma16(Ag1, Br[1], aR);
            aR = mfma16(Ah0, Br[2], aR);  aR = mfma16(Ah1, Br[3], aR);
            aZ = mfma16(Ag0, Bz[0], aZ);  aZ = mfma16(Ag1, Bz[1], aZ);
            aZ = mfma16(Ah0, Bz[2], aZ);  aZ = mfma16(Ah1, Bz[3], aZ);
            aNI = mfma16(Ag0, Bni[0], aNI); aNI = mfma16(Ag1, Bni[1], aNI);
            aNH = mfma16(Ah0, Bnh[0], aNH); aNH = mfma16(Ah1, Bnh[1], aNH);
            #pragma unroll
            for (int j = 0; j < 4; ++j) {
                float r  = sigm(aR[j] + brs);
                float zz = sigm(aZ[j] + bzs);
                float nn = tanhfast(aNI[j] + bnis + r * (aNH[j] + bnhs));
                hg[j] = (1.0f - zz) * nn + zz * hreg[j];
            }
            if (l4 < 2) {
                #pragma unroll
                for (int j = 0; j < 4; ++j) se[l4 * 4 + j][o] = f2bf(hg[j]);
            }
        }
        bar_lgkm();   // P1e

        // ================= P2: bitonic sort (2 rows per wave) =================
        {
            float v0 = bf2f(se[2 * w][ln]);
            float v1 = bf2f(se[2 * w + 1][ln]);
            #pragma unroll
            for (int kk = 2; kk <= 64; kk <<= 1) {
                #pragma unroll
                for (int j = kk >> 1; j > 0; j >>= 1) {
                    float o0 = __shfl_xor(v0, j);
                    float o1 = __shfl_xor(v1, j);
                    bool keepmin = (((ln & kk) == 0) == ((ln & j) == 0));
                    v0 = keepmin ? fminf(v0, o0) : fmaxf(v0, o0);
                    v1 = keepmin ? fminf(v1, o1) : fmaxf(v1, o1);
                }
            }
            se[8 + 2 * w][ln] = f2bf(v0);
            se[9 + 2 * w][ln] = f2bf(v1);
        }
        bar_lgkm();   // P2e

        // ================= P3: a1 = se @ W1^T, shuffle-write =================
        {
            u16x8 As0 = *(const u16x8*)&se[l15][l4 * 8];
            u16x8 As1 = *(const u16x8*)&se[l15][32 + l4 * 8];
            f32x4 c = {0.f, 0.f, 0.f, 0.f};
            c = mfma16(As0, B1f[0], c);
            c = mfma16(As1, B1f[1], c);
            #pragma unroll
            for (int j = 0; j < 4; ++j) {
                int m = l4 * 4 + j;            // p = m>>3 (se half), b = m&7
                int p = m >> 3, b = m & 7;
                int f = p * 64 + o;
                int q = (f & 31) * 4 + (f >> 5);
                a23[b * 4 + (q >> 5)][q & 31] = f2bf(c[j]);
            }
        }
        bar_lgkm();   // P3e

        // ============ P4/P5: waves 0,1 do a2+a3; waves 2,3 commit+prefetch ============
        if (w < 2) {
            const int Rb0 = 16 * w;
            u16x8 a2a = ld8_8al(&a23[Rb0 + l15][l4 * 8]);
            f32x4 z4 = {0.f, 0.f, 0.f, 0.f};
            f32x4 c2[2];
            c2[0] = mfma16(a2a, B2f[0], z4);
            c2[1] = mfma16(a2a, B2f[1], z4);
            #pragma unroll
            for (int nt = 0; nt < 2; ++nt)
                #pragma unroll
                for (int j = 0; j < 4; ++j) {
                    int m = Rb0 + l4 * 4 + j;
                    int b = m >> 2, i2 = m & 3;
                    int n = 16 * nt + l15;
                    int f2 = i2 * 32 + n;
                    int q2 = (f2 & 31) * 4 + (f2 >> 5);
                    a23[b * 4 + (q2 >> 5)][q2 & 31] = f2bf(c2[nt][j]);
                }
            asm volatile("s_waitcnt lgkmcnt(0)" ::: "memory");
            __builtin_amdgcn_sched_barrier(0);
            u16x8 a3a = ld8_8al(&a23[Rb0 + l15][l4 * 8]);
            f32x4 c3[2];
            c3[0] = mfma16(a3a, B3f[0], z4);
            c3[1] = mfma16(a3a, B3f[1], z4);
            #pragma unroll
            for (int nt = 0; nt < 2; ++nt)
                #pragma unroll
                for (int j = 0; j < 4; ++j) {
                    int m = Rb0 + l4 * 4 + j;
                    int b = m >> 2, i3 = m & 3;
                    int n = 16 * nt + l15;
                    w4A[b][i3 * 32 + n] = f2bf(fmaxf(c3[nt][j], 0.0f));
                }
        } else {
            const int rr = (tid - 128) >> 4, c4 = ((tid - 128) & 15) * 4;
            if (t + 1 < LW) {     // commit stash (slot t+1) -> Hin[(t+1)&1]
                u16x4 hv;
                if (l == 0) {
                    hv[0] = f2bf(stf.x); hv[1] = f2bf(stf.y);
                    hv[2] = f2bf(stf.z); hv[3] = f2bf(stf.w);
                } else {
                    u32x2v dv = {st0, st1};
                    hv = __builtin_bit_cast(u16x4, dv);
                }
                *(u16x4*)&Hin[(t + 1) & 1][rr][c4] = hv;
            }
            if (t + 2 < LW) {     // issue loads for slot t+2
                if (l == 0) {
                    stf = *(const float4*)(x + (size_t)(bb0 + rr) * 32768 + (t + 2) * 64 + c4);
                } else {
                    poll_ge(pcnt, (unsigned)(t + 3));
                    const unsigned* sp = ring32
                        + ((size_t)((l - 1) * 8 + g) * D + ((t + 2) & (D - 1))) * 256
                        + rr * 32 + (c4 >> 1);
                    st0 = ld_sys(sp); st1 = ld_sys(sp + 1);
                }
            }
        }
        bar_lgkm();   // P5e
        if (bp && l > 0 && tid == 0)
            st_sys(myccnt, (unsigned)(t + 2));   // slots <= t+1 consumed

        // ================= P6: scores + h update + publish =================
        {
            u16x8 A40 = *(const u16x8*)&w4A[l15][l4 * 8];
            u16x8 A41 = *(const u16x8*)&w4A[l15][32 + l4 * 8];
            u16x8 A42 = *(const u16x8*)&w4A[l15][64 + l4 * 8];
            u16x8 A43 = *(const u16x8*)&w4A[l15][96 + l4 * 8];
            f32x4 cs = {0.f, 0.f, 0.f, 0.f};
            cs = mfma16(A40, B4f[0], cs);
            cs = mfma16(A41, B4f[1], cs);
            cs = mfma16(A42, B4f[2], cs);
            cs = mfma16(A43, B4f[3], cs);

            float hn[4]; u16 hb[4];
            #pragma unroll
            for (int j = 0; j < 4; ++j) {
                hn[j] = hg[j] * sigm(cs[j]);
                hreg[j] = hn[j];
                hb[j] = f2bf(hn[j]);
            }
            if (l4 < 2) {
                #pragma unroll
                for (int j = 0; j < 4; ++j) {
                    int row = l4 * 4 + j;
                    hbf[row][o] = hb[j];
                    if (l == 7) ys[(((size_t)(bb0 + row) << 9) + t) * 64 + o] = hn[j];
                    if (t == 511) hfin[((l << 6) + bb0 + row) * 64 + o] = hn[j];
                }
            }
            if (l < 7) {
                if (bp && t >= D)
                    poll_ge(nccnt, (unsigned)(t - D + 1));
                unsigned* slotp = ring32 + ((size_t)(l * 8 + g) * D + (t & (D - 1))) * 256;
                #pragma unroll
                for (int j = 0; j < 4; ++j) {
                    unsigned ob = (unsigned)__shfl_xor((int)(unsigned)hb[j], 1) & 0xffffu;
                    if (l4 < 2 && !(l15 & 1)) {
                        unsigned word = (unsigned)hb[j] | (ob << 16);
                        st_sys(&slotp[(l4 * 4 + j) * 32 + (o >> 1)], word);
                    }
                }
            }
        }
        if (l < 7) asm volatile("s_waitcnt vmcnt(0) lgkmcnt(0)" ::: "memory");
        else       asm volatile("s_waitcnt lgkmcnt(0)" ::: "memory");
        __builtin_amdgcn_s_barrier();   // P6e
        if (l < 7 && tid == 0)
            st_sys(mycnt, (unsigned)(t + 1));
    }
}

// ---------------- heads: per-window seg + cls logits ----------------
__global__ __launch_bounds__(256) void heads_kernel(
    const float* __restrict__ ys,
    const float* __restrict__ sw1, const float* __restrict__ sb1,
    const float* __restrict__ sw2, const float* __restrict__ sb2,
    const float* __restrict__ sw3, const float* __restrict__ sb3,
    const float* __restrict__ sw4, const float* __restrict__ sb4,
    const float* __restrict__ cw1, const float* __restrict__ cb1,
    const float* __restrict__ cw2, const float* __restrict__ cb2,
    const float* __restrict__ cw3, const float* __restrict__ cb3,
    const float* __restrict__ cw4, const float* __restrict__ cb4,
    float* __restrict__ seg_out, float* __restrict__ cls_tmp)
{
    const int idx = blockIdx.x * 256 + threadIdx.x;
    if (idx >= 64 * LW) return;
    const int b = idx >> 9, t = idx & 511;

    float y[64];
    const float4* yp = (const float4*)(ys + (size_t)idx * 64);
    #pragma unroll
    for (int i = 0; i < 16; ++i) {
        float4 v = yp[i];
        y[4 * i + 0] = v.x; y[4 * i + 1] = v.y; y[4 * i + 2] = v.z; y[4 * i + 3] = v.w;
    }

    float t1[8][4], t2[8][4], t3[8][4];

    // ======== seg head ========
    #pragma unroll
    for (int g = 0; g < 8; ++g)
        #pragma unroll
        for (int s = 0; s < 4; ++s) {
            float acc = sb1[s];
            #pragma unroll
            for (int k = 0; k < 8; ++k) acc = fmaf(y[g * 8 + k], sw1[s * 8 + k], acc);
            t1[g][s] = acc;
        }
    #pragma unroll
    for (int i = 0; i < 8; ++i) {
        float sh[4];
        #pragma unroll
        for (int j = 0; j < 4; ++j) { int m = i * 4 + j; sh[j] = t1[m & 7][m >> 3]; }
        #pragma unroll
        for (int s = 0; s < 4; ++s) {
            float acc = sb2[s];
            #pragma unroll
            for (int j = 0; j < 4; ++j) acc = fmaf(sh[j], sw2[s * 4 + j], acc);
            t2[i][s] = acc;
        }
    }
    #pragma unroll
    for (int i = 0; i < 8; ++i) {
        float sh[4];
        #pragma unroll
        for (int j = 0; j < 4; ++j) { int m = i * 4 + j; sh[j] = t2[m & 7][m >> 3]; }
        #pragma unroll
        for (int s = 0; s < 4; ++s) {
            float acc = sb3[s];
            #pragma unroll
            for (int j = 0; j < 4; ++j) acc = fmaf(sh[j], sw3[s * 4 + j], acc);
            t3[i][s] = acc;
        }
    }
    #pragma unroll
    for (int w = 0; w < 16; ++w) {
        float o4[4];
        #pragma unroll
        for (int s = 0; s < 4; ++s) {
            float acc = sb4[w];
            #pragma unroll
            for (int j = 0; j < 8; ++j) {
                int f = s * 8 + j;
                acc = fmaf(t3[f >> 2][f & 3], sw4[w * 8 + j], acc);
            }
            o4[s] = acc;
        }
        float4 vv = {o4[0], o4[1], o4[2], o4[3]};
        ((float4*)seg_out)[b * 8192 + t * 16 + w] = vv;
    }

    // ======== cls head ========
    #pragma unroll
    for (int g = 0; g < 8; ++g)
        #pragma unroll
        for (int s = 0; s < 4; ++s) {
            float acc = cb1[s];
            #pragma unroll
            for (int k = 0; k < 8; ++k) acc = fmaf(y[g * 8 + k], cw1[s * 8 + k], acc);
            t1[g][s] = acc;
        }
    #pragma unroll
    for (int i = 0; i < 8; ++i) {
        float sh[4];
        #pragma unroll
        for (int j = 0; j < 4; ++j) { int m = i * 4 + j; sh[j] = t1[m & 7][m >> 3]; }
        #pragma unroll
        for (int s = 0; s < 4; ++s) {
            float acc = cb2[s];
            #pragma unroll
            for (int j = 0; j < 4; ++j) acc = fmaf(sh[j], cw2[s * 4 + j], acc);
            t2[i][s] = acc;
        }
    }
    #pragma unroll
    for (int i = 0; i < 8; ++i) {
        float sh[4];
        #pragma unroll
        for (int j = 0; j < 4; ++j) { int m = i * 4 + j; sh[j] = t2[m & 7][m >> 3]; }
        #pragma unroll
        for (int s = 0; s < 4; ++s) {
            float acc = cb3[s];
            #pragma unroll
            for (int j = 0; j < 4; ++j) acc = fmaf(sh[j], cw3[s * 4 + j], acc);
            t3[i][s] = fmaxf(acc, 0.f);
        }
    }
    float cc[4];
    #pragma unroll
    for (int c = 0; c < 4; ++c) {
        float acc = cb4[c];
        #pragma unroll
        for (int k = 0; k < 32; ++k)
            acc = fmaf(t3[k >> 2][k & 3], cw4[c * 32 + k], acc);
        cc[c] = acc;
    }
    float4 cv = {cc[0], cc[1], cc[2], cc[3]};
    ((float4*)cls_tmp)[idx] = cv;
}

// ---------------- cls mean over windows ----------------
__global__ __launch_bounds__(256) void cls_reduce_kernel(
    const float* __restrict__ cls_tmp, float* __restrict__ cls_out)
{
    const int tid = threadIdx.x;
    const int b = tid >> 2, q = tid & 3;
    float ax = 0.f, ay = 0.f, az = 0.f, aw = 0.f;
    for (int t = q; t < 512; t += 4) {
        float4 v = ((const float4*)cls_tmp)[b * 512 + t];
        ax += v.x; ay += v.y; az += v.z; aw += v.w;
    }
    ax += __shfl_xor(ax, 1); ay += __shfl_xor(ay, 1);
    az += __shfl_xor(az, 1); aw += __shfl_xor(aw, 1);
    ax += __shfl_xor(ax, 2); ay += __shfl_xor(ay, 2);
    az += __shfl_xor(az, 2); aw += __shfl_xor(aw, 2);
    if (q == 0) {
        float4 rv = {ax / 512.f, ay / 512.f, az / 512.f, aw / 512.f};
        ((float4*)cls_out)[b] = rv;
    }
}

// ---------------- avg_pool1d(k=11,s=1) with 10 zero history ----------------
__global__ __launch_bounds__(256) void pool_kernel(
    const float* __restrict__ seg, float* __restrict__ pool_out)
{
    const int idx = blockIdx.x * 256 + threadIdx.x;
    if (idx >= 64 * 8192) return;
    const int b = idx >> 13, ll = idx & 8191;
    float ax = 0.f, ay = 0.f, az = 0.f, aw = 0.f;
    int j0 = ll - 10; if (j0 < 0) j0 = 0;
    for (int j = j0; j <= ll; ++j) {
        float4 v = ((const float4*)seg)[b * 8192 + j];
        ax += v.x; ay += v.y; az += v.z; aw += v.w;
    }
    const float inv = 1.0f / 11.0f;
    float4 ov = {ax * inv, ay * inv, az * inv, aw * inv};
    ((float4*)pool_out)[idx] = ov;
}

extern "C" void kernel_launch(void* const* d_in, const int* in_sizes, int n_in,
                              void* d_out, int out_size, void* d_ws, size_t ws_size,
                              hipStream_t stream)
{
    const float* x    = (const float*)d_in[0];
    const float* h0   = (const float*)d_in[1];
    const float* w_ih = (const float*)d_in[2];
    const float* w_hh = (const float*)d_in[3];
    const float* bihp = (const float*)d_in[4];
    const float* bhhp = (const float*)d_in[5];
    const float* aw1  = (const float*)d_in[6];
    const float* aw2  = (const float*)d_in[7];
    const float* aw3  = (const float*)d_in[8];
    const float* aw4  = (const float*)d_in[9];
    const float* sw1  = (const float*)d_in[10];
    const float* sb1  = (const float*)d_in[11];
    const float* sw2  = (const float*)d_in[12];
    const float* sb2  = (const float*)d_in[13];
    const float* sw3  = (const float*)d_in[14];
    const float* sb3  = (const float*)d_in[15];
    const float* sw4  = (const float*)d_in[16];
    const float* sb4  = (const float*)d_in[17];
    const float* cw1  = (const float*)d_in[18];
    const float* cb1  = (const float*)d_in[19];
    const float* cw2  = (const float*)d_in[20];
    const float* cb2  = (const float*)d_in[21];
    const float* cw3  = (const float*)d_in[22];
    const float* cb3  = (const float*)d_in[23];
    const float* cw4  = (const float*)d_in[24];
    const float* cb4  = (const float*)d_in[25];

    float* out      = (float*)d_out;
    float* pool_out = out;                 // (64,8192,4)
    float* cls_out  = out + 2097152;       // (64,4)
    float* ys_out   = out + 2097408;       // (64,512,64)
    float* hfin     = out + 4194560;       // (8,64,64)
    float* seg_out  = out + 4227328;       // (64,8192,4)
    float* cls_tmp  = pool_out;            // staged in pool region, overwritten last

    unsigned* flags  = (unsigned*)d_ws;                   // 32 KB header
    unsigned* ring32 = (unsigned*)((char*)d_ws + 32768);  // 56 x D x 256 u32

    // ring depth: unique slot per timestep if ws allows (no back-pressure)
    size_t slots = (ws_size > 32768) ? (ws_size - 32768) / (56ull * 256 * 4) : 8;
    int D = 512;
    if (slots < 512) {
        D = 8;
        while ((size_t)(D * 2) <= slots && D < 512) D <<= 1;
    }

    init_flags<<<32, 256, 0, stream>>>(flags);
    rnn_kernel<<<64, 256, 0, stream>>>(x, h0, w_ih, w_hh, bihp, bhhp,
                                       aw1, aw2, aw3, aw4, ys_out, hfin,
                                       flags, ring32, D);
    heads_kernel<<<128, 256, 0, stream>>>(ys_out, sw1, sb1, sw2, sb2, sw3, sb3, sw4, sb4,
                                          cw1, cb1, cw2, cb2, cw3, cb3, cw4, cb4,
                                          seg_out, cls_tmp);
    cls_reduce_kernel<<<1, 256, 0, stream>>>(cls_tmp, cls_out);
    pool_kernel<<<2048, 256, 0, stream>>>(seg_out, pool_out);
}

// Round 8
// 1537.068 us; speedup vs baseline: 5.3599x; 1.0920x over previous
//
#include <hip/hip_runtime.h>
#include <math.h>

#define LW  512

typedef unsigned short u16;
typedef float f32x4 __attribute__((ext_vector_type(4)));
typedef u16 u16x4 __attribute__((ext_vector_type(4)));
typedef u16 u16x8 __attribute__((ext_vector_type(8)));
typedef unsigned u32x2v __attribute__((ext_vector_type(2)));
typedef __bf16 bf16x8 __attribute__((ext_vector_type(8)));

__device__ __forceinline__ u16 f2bf(float f) {
    unsigned u = __builtin_bit_cast(unsigned, f);
    unsigned r = (u + 0x7fffu + ((u >> 16) & 1u)) >> 16;
    return (u16)r;
}
__device__ __forceinline__ float bf2f(u16 h) {
    unsigned u = ((unsigned)h) << 16;
    return __builtin_bit_cast(float, u);
}
__device__ __forceinline__ float sigm(float x) {
    return __builtin_amdgcn_rcpf(1.0f + __expf(-x));
}
__device__ __forceinline__ float tanhfast(float x) {
    return 1.0f - 2.0f * __builtin_amdgcn_rcpf(1.0f + __expf(2.0f * x));
}
__device__ __forceinline__ f32x4 mfma16(u16x8 a, u16x8 b, f32x4 c) {
    return __builtin_amdgcn_mfma_f32_16x16x32_bf16(
        __builtin_bit_cast(bf16x8, a), __builtin_bit_cast(bf16x8, b), c, 0, 0, 0);
}
__device__ __forceinline__ u16x8 ld8_8al(const u16* p) {   // 8B-aligned 16B load
    u16x4 lo = *(const u16x4*)p;
    u16x4 hi = *(const u16x4*)(p + 4);
    return __builtin_shufflevector(lo, hi, 0, 1, 2, 3, 4, 5, 6, 7);
}
__device__ __forceinline__ unsigned ld_sys(const unsigned* p) {
    return __hip_atomic_load(p, __ATOMIC_RELAXED, __HIP_MEMORY_SCOPE_SYSTEM);
}
__device__ __forceinline__ void st_sys(unsigned* p, unsigned v) {
    __hip_atomic_store(p, v, __ATOMIC_RELAXED, __HIP_MEMORY_SCOPE_SYSTEM);
}
__device__ __forceinline__ void poll_ge(const unsigned* p, unsigned want) {
    while (ld_sys(p) < want) __builtin_amdgcn_s_sleep(2);
    asm volatile("" ::: "memory");
    __builtin_amdgcn_sched_barrier(0);
}
__device__ __forceinline__ void poll4(const unsigned* p, unsigned want) {
    for (;;) {
        unsigned m0 = ld_sys(p + 0), m1 = ld_sys(p + 1);
        unsigned m2 = ld_sys(p + 2), m3 = ld_sys(p + 3);
        unsigned a = m0 < m1 ? m0 : m1;
        unsigned b = m2 < m3 ? m2 : m3;
        if ((a < b ? a : b) >= want) break;
        __builtin_amdgcn_s_sleep(2);
    }
    asm volatile("" ::: "memory");
    __builtin_amdgcn_sched_barrier(0);
}
__device__ __forceinline__ void bar_lgkm() {
    asm volatile("s_waitcnt lgkmcnt(0)" ::: "memory");
    __builtin_amdgcn_s_barrier();
}

// zero counters
__global__ __launch_bounds__(256) void init_flags(unsigned* f) {
    f[blockIdx.x * 256 + threadIdx.x] = 0u;
}

// ---------------- recurrence: (layer, batch-group) per block ----------------
// R4-proven compute structure (shfl sort). Deferred per-wave flag publish
// (P6e barrier is lgkm-only; flags published at next step's P3 after a free
// vmcnt(0)), plus Hin A-fragment prefetch in P6.
__global__ __launch_bounds__(256, 1) void rnn_kernel(
    const float* __restrict__ x, const float* __restrict__ h0,
    const float* __restrict__ w_ih, const float* __restrict__ w_hh,
    const float* __restrict__ bih, const float* __restrict__ bhh,
    const float* __restrict__ aw1, const float* __restrict__ aw2,
    const float* __restrict__ aw3, const float* __restrict__ aw4,
    float* __restrict__ ys, float* __restrict__ hfin,
    unsigned* __restrict__ flags, unsigned* __restrict__ ring32, int D)
{
    const int l   = blockIdx.x >> 3;   // layer 0..7
    const int g   = blockIdx.x & 7;    // batch group 0..7
    const int bb0 = g * 8;
    const int tid = threadIdx.x;
    const int w   = tid >> 6;          // wave 0..3
    const int ln  = tid & 63;
    const int l15 = ln & 15;
    const int l4  = ln >> 4;
    const bool bp = (D < LW);          // back-pressure only for shallow ring

    unsigned* myflag = flags + (size_t)(l * 8 + g) * 32;         // [4] per-wave
    unsigned* pflag  = flags + (size_t)((l - 1) * 8 + g) * 32;   // producer's [4]
    unsigned* myccnt = flags + 4096 + (size_t)(l * 8 + g) * 32;
    unsigned* nccnt  = flags + 4096 + (size_t)((l + 1) * 8 + g) * 32;

    __shared__ __align__(16) u16 Hin[2][16][72]; // dbl-buffered layer input, rows 8..15 zero
    __shared__ __align__(16) u16 hbf[16][72];    // h state (bf16), rows 8..15 zero
    __shared__ __align__(16) u16 se [16][72];    // rows 0..7 = h, 8..15 = sorted h
    __shared__ __align__(16) u16 a23[32][36];    // a1-shuffled / a2-shuffled overlay
    __shared__ __align__(16) u16 w4A[16][136];   // relu(a3) flat 128, rows 8..15 zero

    for (int i = tid; i < 16 * 72; i += 256) {
        int r = i / 72, c = i % 72;
        if (r >= 8) { Hin[0][r][c] = 0; Hin[1][r][c] = 0; hbf[r][c] = 0; }
    }
    for (int i = tid; i < 16 * 136; i += 256) {
        int r = i / 136;
        if (r >= 8) w4A[r][i % 136] = 0;
    }

    // ---- weight B-fragments into VGPRs (t-invariant) ----
    const int o = 16 * w + l15;
    auto ldw8 = [](const float* p) {
        float4 v0 = *(const float4*)p;
        float4 v1 = *(const float4*)(p + 4);
        u16x8 r;
        r[0] = f2bf(v0.x); r[1] = f2bf(v0.y); r[2] = f2bf(v0.z); r[3] = f2bf(v0.w);
        r[4] = f2bf(v1.x); r[5] = f2bf(v1.y); r[6] = f2bf(v1.z); r[7] = f2bf(v1.w);
        return r;
    };
    const float* ih = w_ih + l * 12288;
    const float* hh = w_hh + l * 12288;
    u16x8 Br[4], Bz[4], Bni[2], Bnh[2], B1f[2], B2f[2], B3f[2], B4f[4];
    Br[0] = ldw8(ih + o * 64 + l4 * 8);        Br[1] = ldw8(ih + o * 64 + 32 + l4 * 8);
    Br[2] = ldw8(hh + o * 64 + l4 * 8);        Br[3] = ldw8(hh + o * 64 + 32 + l4 * 8);
    Bz[0] = ldw8(ih + (64 + o) * 64 + l4 * 8); Bz[1] = ldw8(ih + (64 + o) * 64 + 32 + l4 * 8);
    Bz[2] = ldw8(hh + (64 + o) * 64 + l4 * 8); Bz[3] = ldw8(hh + (64 + o) * 64 + 32 + l4 * 8);
    Bni[0] = ldw8(ih + (128 + o) * 64 + l4 * 8); Bni[1] = ldw8(ih + (128 + o) * 64 + 32 + l4 * 8);
    Bnh[0] = ldw8(hh + (128 + o) * 64 + l4 * 8); Bnh[1] = ldw8(hh + (128 + o) * 64 + 32 + l4 * 8);
    B1f[0] = ldw8(aw1 + l * 4096 + o * 64 + l4 * 8);
    B1f[1] = ldw8(aw1 + l * 4096 + o * 64 + 32 + l4 * 8);
    B2f[0] = ldw8(aw2 + l * 1024 + l15 * 32 + l4 * 8);
    B2f[1] = ldw8(aw2 + l * 1024 + (16 + l15) * 32 + l4 * 8);
    B3f[0] = ldw8(aw3 + l * 1024 + l15 * 32 + l4 * 8);
    B3f[1] = ldw8(aw3 + l * 1024 + (16 + l15) * 32 + l4 * 8);
    #pragma unroll
    for (int kk = 0; kk < 4; ++kk)
        B4f[kk] = ldw8(aw4 + l * 8192 + o * 128 + kk * 32 + l4 * 8);

    const float brs  = bih[l * 192 + o]       + bhh[l * 192 + o];
    const float bzs  = bih[l * 192 + 64 + o]  + bhh[l * 192 + 64 + o];
    const float bnis = bih[l * 192 + 128 + o];
    const float bnhs = bhh[l * 192 + 128 + o];

    float hreg[4];
    {
        float hv = h0[l * 64 + o];
        #pragma unroll
        for (int j = 0; j < 4; ++j) hreg[j] = hv;
        if (l4 < 2) {
            u16 hb = f2bf(hv);
            #pragma unroll
            for (int j = 0; j < 4; ++j) hbf[l4 * 4 + j][o] = hb;
        }
    }

    // ---- prologue: stage slot 0 into Hin[0]; slot 1 into stash regs ----
    float4 stf = {0.f, 0.f, 0.f, 0.f};
    unsigned st0 = 0, st1 = 0;
    if (w >= 2) {
        const int rr = (tid - 128) >> 4, c4 = ((tid - 128) & 15) * 4;
        if (l == 0) {
            float4 a = *(const float4*)(x + (size_t)(bb0 + rr) * 32768 + c4);
            u16x4 hv;
            hv[0] = f2bf(a.x); hv[1] = f2bf(a.y); hv[2] = f2bf(a.z); hv[3] = f2bf(a.w);
            *(u16x4*)&Hin[0][rr][c4] = hv;
            stf = *(const float4*)(x + (size_t)(bb0 + rr) * 32768 + 64 + c4);
        } else {
            poll4(pflag, 1u);
            const unsigned* sp0 = ring32 + ((size_t)((l - 1) * 8 + g) * D + 0) * 256 + rr * 32 + (c4 >> 1);
            unsigned a0 = ld_sys(sp0), a1 = ld_sys(sp0 + 1);
            u32x2v dv = {a0, a1};
            *(u16x4*)&Hin[0][rr][c4] = __builtin_bit_cast(u16x4, dv);
            poll4(pflag, 2u);
            const unsigned* sp1 = ring32 + ((size_t)((l - 1) * 8 + g) * D + 1) * 256 + rr * 32 + (c4 >> 1);
            st0 = ld_sys(sp1); st1 = ld_sys(sp1 + 1);
        }
    }
    __syncthreads();

    // prefetched A-fragments of Hin for the upcoming P1
    u16x8 pAg0 = *(const u16x8*)&Hin[0][l15][l4 * 8];
    u16x8 pAg1 = *(const u16x8*)&Hin[0][l15][32 + l4 * 8];

    for (int t = 0; t < LW; ++t) {
        float hg[4];
        // ================= P1: GRU (A-input prefetched into pAg) =================
        {
            u16x8 Ah0 = *(const u16x8*)&hbf[l15][l4 * 8];
            u16x8 Ah1 = *(const u16x8*)&hbf[l15][32 + l4 * 8];
            f32x4 z4 = {0.f, 0.f, 0.f, 0.f};
            f32x4 aR = z4, aZ = z4, aNI = z4, aNH = z4;
            aR = mfma16(pAg0, Br[0], aR);  aR = mfma16(pAg1, Br[1], aR);
            aR = mfma16(Ah0, Br[2], aR);   aR = mfma16(Ah1, Br[3], aR);
            aZ = mfma16(pAg0, Bz[0], aZ);  aZ = mfma16(pAg1, Bz[1], aZ);
            aZ = mfma16(Ah0, Bz[2], aZ);   aZ = mfma16(Ah1, Bz[3], aZ);
            aNI = mfma16(pAg0, Bni[0], aNI); aNI = mfma16(pAg1, Bni[1], aNI);
            aNH = mfma16(Ah0, Bnh[0], aNH);  aNH = mfma16(Ah1, Bnh[1], aNH);
            #pragma unroll
            for (int j = 0; j < 4; ++j) {
                float r  = sigm(aR[j] + brs);
                float zz = sigm(aZ[j] + bzs);
                float nn = tanhfast(aNI[j] + bnis + r * (aNH[j] + bnhs));
                hg[j] = (1.0f - zz) * nn + zz * hreg[j];
            }
            if (l4 < 2) {
                #pragma unroll
                for (int j = 0; j < 4; ++j) se[l4 * 4 + j][o] = f2bf(hg[j]);
            }
        }
        bar_lgkm();   // P1e

        // ================= P2: bitonic sort (R4-proven __shfl_xor) =================
        {
            float v0 = bf2f(se[2 * w][ln]);
            float v1 = bf2f(se[2 * w + 1][ln]);
            #pragma unroll
            for (int kk = 2; kk <= 64; kk <<= 1) {
                #pragma unroll
                for (int j = kk >> 1; j > 0; j >>= 1) {
                    float o0 = __shfl_xor(v0, j);
                    float o1 = __shfl_xor(v1, j);
                    bool keepmin = (((ln & kk) == 0) == ((ln & j) == 0));
                    v0 = keepmin ? fminf(v0, o0) : fmaxf(v0, o0);
                    v1 = keepmin ? fminf(v1, o1) : fmaxf(v1, o1);
                }
            }
            se[8 + 2 * w][ln] = f2bf(v0);
            se[9 + 2 * w][ln] = f2bf(v1);
        }
        bar_lgkm();   // P2e

        // ====== P3: deferred per-wave flag publish (stores of step t-1 long acked) ======
        if (l < 7) {
            asm volatile("s_waitcnt vmcnt(0)" ::: "memory");
            if (ln == 0) st_sys(myflag + w, (unsigned)t);
        }
        // ================= P3: a1 = se @ W1^T, shuffle-write =================
        {
            u16x8 As0 = *(const u16x8*)&se[l15][l4 * 8];
            u16x8 As1 = *(const u16x8*)&se[l15][32 + l4 * 8];
            f32x4 c = {0.f, 0.f, 0.f, 0.f};
            c = mfma16(As0, B1f[0], c);
            c = mfma16(As1, B1f[1], c);
            #pragma unroll
            for (int j = 0; j < 4; ++j) {
                int m = l4 * 4 + j;            // p = m>>3 (se half), b = m&7
                int p = m >> 3, b = m & 7;
                int f = p * 64 + o;
                int q = (f & 31) * 4 + (f >> 5);
                a23[b * 4 + (q >> 5)][q & 31] = f2bf(c[j]);
            }
        }
        bar_lgkm();   // P3e

        // ============ P4/P5: waves 0,1 do a2+a3; waves 2,3 commit+prefetch ============
        if (w < 2) {
            const int Rb0 = 16 * w;
            u16x8 a2a = ld8_8al(&a23[Rb0 + l15][l4 * 8]);
            f32x4 z4 = {0.f, 0.f, 0.f, 0.f};
            f32x4 c2[2];
            c2[0] = mfma16(a2a, B2f[0], z4);
            c2[1] = mfma16(a2a, B2f[1], z4);
            #pragma unroll
            for (int nt = 0; nt < 2; ++nt)
                #pragma unroll
                for (int j = 0; j < 4; ++j) {
                    int m = Rb0 + l4 * 4 + j;
                    int b = m >> 2, i2 = m & 3;
                    int n = 16 * nt + l15;
                    int f2 = i2 * 32 + n;
                    int q2 = (f2 & 31) * 4 + (f2 >> 5);
                    a23[b * 4 + (q2 >> 5)][q2 & 31] = f2bf(c2[nt][j]);
                }
            asm volatile("s_waitcnt lgkmcnt(0)" ::: "memory");
            __builtin_amdgcn_sched_barrier(0);
            u16x8 a3a = ld8_8al(&a23[Rb0 + l15][l4 * 8]);
            f32x4 c3[2];
            c3[0] = mfma16(a3a, B3f[0], z4);
            c3[1] = mfma16(a3a, B3f[1], z4);
            #pragma unroll
            for (int nt = 0; nt < 2; ++nt)
                #pragma unroll
                for (int j = 0; j < 4; ++j) {
                    int m = Rb0 + l4 * 4 + j;
                    int b = m >> 2, i3 = m & 3;
                    int n = 16 * nt + l15;
                    w4A[b][i3 * 32 + n] = f2bf(fmaxf(c3[nt][j], 0.0f));
                }
        } else {
            const int rr = (tid - 128) >> 4, c4 = ((tid - 128) & 15) * 4;
            if (t + 1 < LW) {     // commit stash (slot t+1) -> Hin[(t+1)&1]
                u16x4 hv;
                if (l == 0) {
                    hv[0] = f2bf(stf.x); hv[1] = f2bf(stf.y);
                    hv[2] = f2bf(stf.z); hv[3] = f2bf(stf.w);
                } else {
                    u32x2v dv = {st0, st1};
                    hv = __builtin_bit_cast(u16x4, dv);
                }
                *(u16x4*)&Hin[(t + 1) & 1][rr][c4] = hv;
            }
            if (t + 2 < LW) {     // issue loads for slot t+2
                if (l == 0) {
                    stf = *(const float4*)(x + (size_t)(bb0 + rr) * 32768 + (t + 2) * 64 + c4);
                } else {
                    poll4(pflag, (unsigned)(t + 3));
                    const unsigned* sp = ring32
                        + ((size_t)((l - 1) * 8 + g) * D + ((t + 2) & (D - 1))) * 256
                        + rr * 32 + (c4 >> 1);
                    st0 = ld_sys(sp); st1 = ld_sys(sp + 1);
                }
            }
        }
        bar_lgkm();   // P5e
        if (bp && l > 0 && tid == 0)
            st_sys(myccnt, (unsigned)(t + 2));   // slots <= t+1 consumed

        // ================= P6: scores + h update + publish =================
        {
            u16x8 A40 = *(const u16x8*)&w4A[l15][l4 * 8];
            u16x8 A41 = *(const u16x8*)&w4A[l15][32 + l4 * 8];
            u16x8 A42 = *(const u16x8*)&w4A[l15][64 + l4 * 8];
            u16x8 A43 = *(const u16x8*)&w4A[l15][96 + l4 * 8];
            // prefetch next step's input fragments (committed at P4, stable after P5e)
            pAg0 = *(const u16x8*)&Hin[(t + 1) & 1][l15][l4 * 8];
            pAg1 = *(const u16x8*)&Hin[(t + 1) & 1][l15][32 + l4 * 8];
            f32x4 cs = {0.f, 0.f, 0.f, 0.f};
            cs = mfma16(A40, B4f[0], cs);
            cs = mfma16(A41, B4f[1], cs);
            cs = mfma16(A42, B4f[2], cs);
            cs = mfma16(A43, B4f[3], cs);

            if (bp && l < 7 && t >= D) {   // ring back-pressure (shallow ring only)
                poll_ge(nccnt, (unsigned)(t - D + 1));
            }
            unsigned* slotp = ring32 + ((size_t)(l * 8 + g) * D + (t & (D - 1))) * 256;
            float hn[4]; u16 hb[4];
            #pragma unroll
            for (int j = 0; j < 4; ++j) {
                hn[j] = hg[j] * sigm(cs[j]);
                hreg[j] = hn[j];
                hb[j] = f2bf(hn[j]);
            }
            if (l4 < 2) {
                #pragma unroll
                for (int j = 0; j < 4; ++j) {
                    int row = l4 * 4 + j;
                    hbf[row][o] = hb[j];
                    if (l == 7) ys[(((size_t)(bb0 + row) << 9) + t) * 64 + o] = hn[j];
                    if (t == 511) hfin[((l << 6) + bb0 + row) * 64 + o] = hn[j];
                }
            }
            if (l < 7) {
                #pragma unroll
                for (int j = 0; j < 4; ++j) {
                    unsigned ob = (unsigned)__shfl_xor((int)(unsigned)hb[j], 1) & 0xffffu;
                    if (l4 < 2 && !(l15 & 1)) {
                        unsigned word = (unsigned)hb[j] | (ob << 16);
                        st_sys(&slotp[(l4 * 4 + j) * 32 + (o >> 1)], word);
                    }
                }
            }
        }
        bar_lgkm();   // P6e (lgkm only; ring stores drain in background)
    }

    // epilogue: final flag so consumer's last prefetches can complete
    if (l < 7) {
        asm volatile("s_waitcnt vmcnt(0)" ::: "memory");
        if (ln == 0) st_sys(myflag + w, 512u);
    }
}

// ---------------- heads: per-window seg + cls logits ----------------
__global__ __launch_bounds__(256) void heads_kernel(
    const float* __restrict__ ys,
    const float* __restrict__ sw1, const float* __restrict__ sb1,
    const float* __restrict__ sw2, const float* __restrict__ sb2,
    const float* __restrict__ sw3, const float* __restrict__ sb3,
    const float* __restrict__ sw4, const float* __restrict__ sb4,
    const float* __restrict__ cw1, const float* __restrict__ cb1,
    const float* __restrict__ cw2, const float* __restrict__ cb2,
    const float* __restrict__ cw3, const float* __restrict__ cb3,
    const float* __restrict__ cw4, const float* __restrict__ cb4,
    float* __restrict__ seg_out, float* __restrict__ cls_tmp)
{
    const int idx = blockIdx.x * 256 + threadIdx.x;
    if (idx >= 64 * LW) return;
    const int b = idx >> 9, t = idx & 511;

    float y[64];
    const float4* yp = (const float4*)(ys + (size_t)idx * 64);
    #pragma unroll
    for (int i = 0; i < 16; ++i) {
        float4 v = yp[i];
        y[4 * i + 0] = v.x; y[4 * i + 1] = v.y; y[4 * i + 2] = v.z; y[4 * i + 3] = v.w;
    }

    float t1[8][4], t2[8][4], t3[8][4];

    // ======== seg head ========
    #pragma unroll
    for (int g = 0; g < 8; ++g)
        #pragma unroll
        for (int s = 0; s < 4; ++s) {
            float acc = sb1[s];
            #pragma unroll
            for (int k = 0; k < 8; ++k) acc = fmaf(y[g * 8 + k], sw1[s * 8 + k], acc);
            t1[g][s] = acc;
        }
    #pragma unroll
    for (int i = 0; i < 8; ++i) {
        float sh[4];
        #pragma unroll
        for (int j = 0; j < 4; ++j) { int m = i * 4 + j; sh[j] = t1[m & 7][m >> 3]; }
        #pragma unroll
        for (int s = 0; s < 4; ++s) {
            float acc = sb2[s];
            #pragma unroll
            for (int j = 0; j < 4; ++j) acc = fmaf(sh[j], sw2[s * 4 + j], acc);
            t2[i][s] = acc;
        }
    }
    #pragma unroll
    for (int i = 0; i < 8; ++i) {
        float sh[4];
        #pragma unroll
        for (int j = 0; j < 4; ++j) { int m = i * 4 + j; sh[j] = t2[m & 7][m >> 3]; }
        #pragma unroll
        for (int s = 0; s < 4; ++s) {
            float acc = sb3[s];
            #pragma unroll
            for (int j = 0; j < 4; ++j) acc = fmaf(sh[j], sw3[s * 4 + j], acc);
            t3[i][s] = acc;
        }
    }
    #pragma unroll
    for (int w = 0; w < 16; ++w) {
        float o4[4];
        #pragma unroll
        for (int s = 0; s < 4; ++s) {
            float acc = sb4[w];
            #pragma unroll
            for (int j = 0; j < 8; ++j) {
                int f = s * 8 + j;
                acc = fmaf(t3[f >> 2][f & 3], sw4[w * 8 + j], acc);
            }
            o4[s] = acc;
        }
        float4 vv = {o4[0], o4[1], o4[2], o4[3]};
        ((float4*)seg_out)[b * 8192 + t * 16 + w] = vv;
    }

    // ======== cls head ========
    #pragma unroll
    for (int g = 0; g < 8; ++g)
        #pragma unroll
        for (int s = 0; s < 4; ++s) {
            float acc = cb1[s];
            #pragma unroll
            for (int k = 0; k < 8; ++k) acc = fmaf(y[g * 8 + k], cw1[s * 8 + k], acc);
            t1[g][s] = acc;
        }
    #pragma unroll
    for (int i = 0; i < 8; ++i) {
        float sh[4];
        #pragma unroll
        for (int j = 0; j < 4; ++j) { int m = i * 4 + j; sh[j] = t1[m & 7][m >> 3]; }
        #pragma unroll
        for (int s = 0; s < 4; ++s) {
            float acc = cb2[s];
            #pragma unroll
            for (int j = 0; j < 4; ++j) acc = fmaf(sh[j], cw2[s * 4 + j], acc);
            t2[i][s] = acc;
        }
    }
    #pragma unroll
    for (int i = 0; i < 8; ++i) {
        float sh[4];
        #pragma unroll
        for (int j = 0; j < 4; ++j) { int m = i * 4 + j; sh[j] = t2[m & 7][m >> 3]; }
        #pragma unroll
        for (int s = 0; s < 4; ++s) {
            float acc = cb3[s];
            #pragma unroll
            for (int j = 0; j < 4; ++j) acc = fmaf(sh[j], cw3[s * 4 + j], acc);
            t3[i][s] = fmaxf(acc, 0.f);
        }
    }
    float cc[4];
    #pragma unroll
    for (int c = 0; c < 4; ++c) {
        float acc = cb4[c];
        #pragma unroll
        for (int k = 0; k < 32; ++k)
            acc = fmaf(t3[k >> 2][k & 3], cw4[c * 32 + k], acc);
        cc[c] = acc;
    }
    float4 cv = {cc[0], cc[1], cc[2], cc[3]};
    ((float4*)cls_tmp)[idx] = cv;
}

// ---------------- cls mean over windows ----------------
__global__ __launch_bounds__(256) void cls_reduce_kernel(
    const float* __restrict__ cls_tmp, float* __restrict__ cls_out)
{
    const int tid = threadIdx.x;
    const int b = tid >> 2, q = tid & 3;
    float ax = 0.f, ay = 0.f, az = 0.f, aw = 0.f;
    for (int t = q; t < 512; t += 4) {
        float4 v = ((const float4*)cls_tmp)[b * 512 + t];
        ax += v.x; ay += v.y; az += v.z; aw += v.w;
    }
    ax += __shfl_xor(ax, 1); ay += __shfl_xor(ay, 1);
    az += __shfl_xor(az, 1); aw += __shfl_xor(aw, 1);
    ax += __shfl_xor(ax, 2); ay += __shfl_xor(ay, 2);
    az += __shfl_xor(az, 2); aw += __shfl_xor(aw, 2);
    if (q == 0) {
        float4 rv = {ax / 512.f, ay / 512.f, az / 512.f, aw / 512.f};
        ((float4*)cls_out)[b] = rv;
    }
}

// ---------------- avg_pool1d(k=11,s=1) with 10 zero history ----------------
__global__ __launch_bounds__(256) void pool_kernel(
    const float* __restrict__ seg, float* __restrict__ pool_out)
{
    const int idx = blockIdx.x * 256 + threadIdx.x;
    if (idx >= 64 * 8192) return;
    const int b = idx >> 13, ll = idx & 8191;
    float ax = 0.f, ay = 0.f, az = 0.f, aw = 0.f;
    int j0 = ll - 10; if (j0 < 0) j0 = 0;
    for (int j = j0; j <= ll; ++j) {
        float4 v = ((const float4*)seg)[b * 8192 + j];
        ax += v.x; ay += v.y; az += v.z; aw += v.w;
    }
    const float inv = 1.0f / 11.0f;
    float4 ov = {ax * inv, ay * inv, az * inv, aw * inv};
    ((float4*)pool_out)[idx] = ov;
}

extern "C" void kernel_launch(void* const* d_in, const int* in_sizes, int n_in,
                              void* d_out, int out_size, void* d_ws, size_t ws_size,
                              hipStream_t stream)
{
    const float* x    = (const float*)d_in[0];
    const float* h0   = (const float*)d_in[1];
    const float* w_ih = (const float*)d_in[2];
    const float* w_hh = (const float*)d_in[3];
    const float* bihp = (const float*)d_in[4];
    const float* bhhp = (const float*)d_in[5];
    const float* aw1  = (const float*)d_in[6];
    const float* aw2  = (const float*)d_in[7];
    const float* aw3  = (const float*)d_in[8];
    const float* aw4  = (const float*)d_in[9];
    const float* sw1  = (const float*)d_in[10];
    const float* sb1  = (const float*)d_in[11];
    const float* sw2  = (const float*)d_in[12];
    const float* sb2  = (const float*)d_in[13];
    const float* sw3  = (const float*)d_in[14];
    const float* sb3  = (const float*)d_in[15];
    const float* sw4  = (const float*)d_in[16];
    const float* sb4  = (const float*)d_in[17];
    const float* cw1  = (const float*)d_in[18];
    const float* cb1  = (const float*)d_in[19];
    const float* cw2  = (const float*)d_in[20];
    const float* cb2  = (const float*)d_in[21];
    const float* cw3  = (const float*)d_in[22];
    const float* cb3  = (const float*)d_in[23];
    const float* cw4  = (const float*)d_in[24];
    const float* cb4  = (const float*)d_in[25];

    float* out      = (float*)d_out;
    float* pool_out = out;                 // (64,8192,4)
    float* cls_out  = out + 2097152;       // (64,4)
    float* ys_out   = out + 2097408;       // (64,512,64)
    float* hfin     = out + 4194560;       // (8,64,64)
    float* seg_out  = out + 4227328;       // (64,8192,4)
    float* cls_tmp  = pool_out;            // staged in pool region, overwritten last

    unsigned* flags  = (unsigned*)d_ws;                   // 32 KB header
    unsigned* ring32 = (unsigned*)((char*)d_ws + 32768);  // 56 x D x 256 u32

    // ring depth: unique slot per timestep if ws allows (no back-pressure)
    size_t slots = (ws_size > 32768) ? (ws_size - 32768) / (56ull * 256 * 4) : 8;
    int D = 512;
    if (slots < 512) {
        D = 8;
        while ((size_t)(D * 2) <= slots && D < 512) D <<= 1;
    }

    init_flags<<<32, 256, 0, stream>>>(flags);
    rnn_kernel<<<64, 256, 0, stream>>>(x, h0, w_ih, w_hh, bihp, bhhp,
                                       aw1, aw2, aw3, aw4, ys_out, hfin,
                                       flags, ring32, D);
    heads_kernel<<<128, 256, 0, stream>>>(ys_out, sw1, sb1, sw2, sb2, sw3, sb3, sw4, sb4,
                                          cw1, cb1, cw2, cb2, cw3, cb3, cw4, cb4,
                                          seg_out, cls_tmp);
    cls_reduce_kernel<<<1, 256, 0, stream>>>(cls_tmp, cls_out);
    pool_kernel<<<2048, 256, 0, stream>>>(seg_out, pool_out);
}

// Round 9
// 1353.516 us; speedup vs baseline: 6.0868x; 1.1356x over previous
//
#include <hip/hip_runtime.h>
#include <math.h>

#define LW  512

typedef unsigned short u16;
typedef float f32x4 __attribute__((ext_vector_type(4)));
typedef u16 u16x4 __attribute__((ext_vector_type(4)));
typedef u16 u16x8 __attribute__((ext_vector_type(8)));
typedef unsigned u32x2v __attribute__((ext_vector_type(2)));
typedef __bf16 bf16x8 __attribute__((ext_vector_type(8)));

__device__ __forceinline__ u16 f2bf(float f) {
    unsigned u = __builtin_bit_cast(unsigned, f);
    unsigned r = (u + 0x7fffu + ((u >> 16) & 1u)) >> 16;
    return (u16)r;
}
__device__ __forceinline__ float bf2f(u16 h) {
    unsigned u = ((unsigned)h) << 16;
    return __builtin_bit_cast(float, u);
}
__device__ __forceinline__ float sigm(float x) {
    return __builtin_amdgcn_rcpf(1.0f + __expf(-x));
}
__device__ __forceinline__ float tanhfast(float x) {
    return 1.0f - 2.0f * __builtin_amdgcn_rcpf(1.0f + __expf(2.0f * x));
}
__device__ __forceinline__ f32x4 mfma16(u16x8 a, u16x8 b, f32x4 c) {
    return __builtin_amdgcn_mfma_f32_16x16x32_bf16(
        __builtin_bit_cast(bf16x8, a), __builtin_bit_cast(bf16x8, b), c, 0, 0, 0);
}
__device__ __forceinline__ u16x8 ld8_8al(const u16* p) {   // 8B-aligned 16B load
    u16x4 lo = *(const u16x4*)p;
    u16x4 hi = *(const u16x4*)(p + 4);
    return __builtin_shufflevector(lo, hi, 0, 1, 2, 3, 4, 5, 6, 7);
}
__device__ __forceinline__ unsigned ld_sys(const unsigned* p) {
    return __hip_atomic_load(p, __ATOMIC_RELAXED, __HIP_MEMORY_SCOPE_SYSTEM);
}
__device__ __forceinline__ void st_sys(unsigned* p, unsigned v) {
    __hip_atomic_store(p, v, __ATOMIC_RELAXED, __HIP_MEMORY_SCOPE_SYSTEM);
}
__device__ __forceinline__ void poll_ge(const unsigned* p, unsigned want) {
    while (ld_sys(p) < want) __builtin_amdgcn_s_sleep(2);
    asm volatile("" ::: "memory");
    __builtin_amdgcn_sched_barrier(0);
}
__device__ __forceinline__ void poll4(const unsigned* p, unsigned want) {
    for (;;) {
        unsigned m0 = ld_sys(p + 0), m1 = ld_sys(p + 1);
        unsigned m2 = ld_sys(p + 2), m3 = ld_sys(p + 3);
        unsigned a = m0 < m1 ? m0 : m1;
        unsigned b = m2 < m3 ? m2 : m3;
        if ((a < b ? a : b) >= want) break;
        __builtin_amdgcn_s_sleep(2);
    }
    asm volatile("" ::: "memory");
    __builtin_amdgcn_sched_barrier(0);
}
__device__ __forceinline__ void bar_lgkm() {
    asm volatile("s_waitcnt lgkmcnt(0)" ::: "memory");
    __builtin_amdgcn_s_barrier();
}

// ---- hybrid lane exchange for the sort ----
// J=1,2: SINGLE quad_perm mov_dpp (never composed — composed double-DPP was the
//        R5-R7 deterministic miscompile). J=4,8,16: ds_swizzle with ISA-doc
//        bit-mode offsets (identical to what __shfl_xor emits). J=32: __shfl_xor
//        (swizzle cannot cross 32-lane halves).
template<int CTRL> __device__ __forceinline__ float dppf(float v) {
    return __builtin_bit_cast(float,
        __builtin_amdgcn_mov_dpp(__builtin_bit_cast(int, v), CTRL, 0xF, 0xF, false));
}
template<int OFF> __device__ __forceinline__ float swzf(float v) {
    return __builtin_bit_cast(float,
        __builtin_amdgcn_ds_swizzle(__builtin_bit_cast(int, v), OFF));
}
template<int J> __device__ __forceinline__ float xch(float v) {
    if constexpr (J == 1)  return dppf<0xB1>(v);        // quad_perm [1,0,3,2]
    else if constexpr (J == 2)  return dppf<0x4E>(v);   // quad_perm [2,3,0,1]
    else if constexpr (J == 4)  return swzf<0x101F>(v); // bit-mode xor4
    else if constexpr (J == 8)  return swzf<0x201F>(v); // bit-mode xor8
    else if constexpr (J == 16) return swzf<0x401F>(v); // bit-mode xor16
    else return __shfl_xor(v, 32);
}
#define STG(KK, J) { \
    float o0 = xch<J>(v0), o1 = xch<J>(v1); \
    bool keepmin = (((ln & KK) == 0) == ((ln & J) == 0)); \
    v0 = keepmin ? fminf(v0, o0) : fmaxf(v0, o0); \
    v1 = keepmin ? fminf(v1, o1) : fmaxf(v1, o1); }

// zero counters
__global__ __launch_bounds__(256) void init_flags(unsigned* f) {
    f[blockIdx.x * 256 + threadIdx.x] = 0u;
}

// ---------------- recurrence: (layer, batch-group) per block ----------------
// R8-proven structure (deferred per-wave flags, pAg prefetch). Single change:
// P2 sort exchanges use the hybrid DPP/ds_swizzle path above.
__global__ __launch_bounds__(256, 1) void rnn_kernel(
    const float* __restrict__ x, const float* __restrict__ h0,
    const float* __restrict__ w_ih, const float* __restrict__ w_hh,
    const float* __restrict__ bih, const float* __restrict__ bhh,
    const float* __restrict__ aw1, const float* __restrict__ aw2,
    const float* __restrict__ aw3, const float* __restrict__ aw4,
    float* __restrict__ ys, float* __restrict__ hfin,
    unsigned* __restrict__ flags, unsigned* __restrict__ ring32, int D)
{
    const int l   = blockIdx.x >> 3;   // layer 0..7
    const int g   = blockIdx.x & 7;    // batch group 0..7
    const int bb0 = g * 8;
    const int tid = threadIdx.x;
    const int w   = tid >> 6;          // wave 0..3
    const int ln  = tid & 63;
    const int l15 = ln & 15;
    const int l4  = ln >> 4;
    const bool bp = (D < LW);          // back-pressure only for shallow ring

    unsigned* myflag = flags + (size_t)(l * 8 + g) * 32;         // [4] per-wave
    unsigned* pflag  = flags + (size_t)((l - 1) * 8 + g) * 32;   // producer's [4]
    unsigned* myccnt = flags + 4096 + (size_t)(l * 8 + g) * 32;
    unsigned* nccnt  = flags + 4096 + (size_t)((l + 1) * 8 + g) * 32;

    __shared__ __align__(16) u16 Hin[2][16][72]; // dbl-buffered layer input, rows 8..15 zero
    __shared__ __align__(16) u16 hbf[16][72];    // h state (bf16), rows 8..15 zero
    __shared__ __align__(16) u16 se [16][72];    // rows 0..7 = h, 8..15 = sorted h
    __shared__ __align__(16) u16 a23[32][36];    // a1-shuffled / a2-shuffled overlay
    __shared__ __align__(16) u16 w4A[16][136];   // relu(a3) flat 128, rows 8..15 zero

    for (int i = tid; i < 16 * 72; i += 256) {
        int r = i / 72, c = i % 72;
        if (r >= 8) { Hin[0][r][c] = 0; Hin[1][r][c] = 0; hbf[r][c] = 0; }
    }
    for (int i = tid; i < 16 * 136; i += 256) {
        int r = i / 136;
        if (r >= 8) w4A[r][i % 136] = 0;
    }

    // ---- weight B-fragments into VGPRs (t-invariant) ----
    const int o = 16 * w + l15;
    auto ldw8 = [](const float* p) {
        float4 v0 = *(const float4*)p;
        float4 v1 = *(const float4*)(p + 4);
        u16x8 r;
        r[0] = f2bf(v0.x); r[1] = f2bf(v0.y); r[2] = f2bf(v0.z); r[3] = f2bf(v0.w);
        r[4] = f2bf(v1.x); r[5] = f2bf(v1.y); r[6] = f2bf(v1.z); r[7] = f2bf(v1.w);
        return r;
    };
    const float* ih = w_ih + l * 12288;
    const float* hh = w_hh + l * 12288;
    u16x8 Br[4], Bz[4], Bni[2], Bnh[2], B1f[2], B2f[2], B3f[2], B4f[4];
    Br[0] = ldw8(ih + o * 64 + l4 * 8);        Br[1] = ldw8(ih + o * 64 + 32 + l4 * 8);
    Br[2] = ldw8(hh + o * 64 + l4 * 8);        Br[3] = ldw8(hh + o * 64 + 32 + l4 * 8);
    Bz[0] = ldw8(ih + (64 + o) * 64 + l4 * 8); Bz[1] = ldw8(ih + (64 + o) * 64 + 32 + l4 * 8);
    Bz[2] = ldw8(hh + (64 + o) * 64 + l4 * 8); Bz[3] = ldw8(hh + (64 + o) * 64 + 32 + l4 * 8);
    Bni[0] = ldw8(ih + (128 + o) * 64 + l4 * 8); Bni[1] = ldw8(ih + (128 + o) * 64 + 32 + l4 * 8);
    Bnh[0] = ldw8(hh + (128 + o) * 64 + l4 * 8); Bnh[1] = ldw8(hh + (128 + o) * 64 + 32 + l4 * 8);
    B1f[0] = ldw8(aw1 + l * 4096 + o * 64 + l4 * 8);
    B1f[1] = ldw8(aw1 + l * 4096 + o * 64 + 32 + l4 * 8);
    B2f[0] = ldw8(aw2 + l * 1024 + l15 * 32 + l4 * 8);
    B2f[1] = ldw8(aw2 + l * 1024 + (16 + l15) * 32 + l4 * 8);
    B3f[0] = ldw8(aw3 + l * 1024 + l15 * 32 + l4 * 8);
    B3f[1] = ldw8(aw3 + l * 1024 + (16 + l15) * 32 + l4 * 8);
    #pragma unroll
    for (int kk = 0; kk < 4; ++kk)
        B4f[kk] = ldw8(aw4 + l * 8192 + o * 128 + kk * 32 + l4 * 8);

    const float brs  = bih[l * 192 + o]       + bhh[l * 192 + o];
    const float bzs  = bih[l * 192 + 64 + o]  + bhh[l * 192 + 64 + o];
    const float bnis = bih[l * 192 + 128 + o];
    const float bnhs = bhh[l * 192 + 128 + o];

    float hreg[4];
    {
        float hv = h0[l * 64 + o];
        #pragma unroll
        for (int j = 0; j < 4; ++j) hreg[j] = hv;
        if (l4 < 2) {
            u16 hb = f2bf(hv);
            #pragma unroll
            for (int j = 0; j < 4; ++j) hbf[l4 * 4 + j][o] = hb;
        }
    }

    // ---- prologue: stage slot 0 into Hin[0]; slot 1 into stash regs ----
    float4 stf = {0.f, 0.f, 0.f, 0.f};
    unsigned st0 = 0, st1 = 0;
    if (w >= 2) {
        const int rr = (tid - 128) >> 4, c4 = ((tid - 128) & 15) * 4;
        if (l == 0) {
            float4 a = *(const float4*)(x + (size_t)(bb0 + rr) * 32768 + c4);
            u16x4 hv;
            hv[0] = f2bf(a.x); hv[1] = f2bf(a.y); hv[2] = f2bf(a.z); hv[3] = f2bf(a.w);
            *(u16x4*)&Hin[0][rr][c4] = hv;
            stf = *(const float4*)(x + (size_t)(bb0 + rr) * 32768 + 64 + c4);
        } else {
            poll4(pflag, 1u);
            const unsigned* sp0 = ring32 + ((size_t)((l - 1) * 8 + g) * D + 0) * 256 + rr * 32 + (c4 >> 1);
            unsigned a0 = ld_sys(sp0), a1 = ld_sys(sp0 + 1);
            u32x2v dv = {a0, a1};
            *(u16x4*)&Hin[0][rr][c4] = __builtin_bit_cast(u16x4, dv);
            poll4(pflag, 2u);
            const unsigned* sp1 = ring32 + ((size_t)((l - 1) * 8 + g) * D + 1) * 256 + rr * 32 + (c4 >> 1);
            st0 = ld_sys(sp1); st1 = ld_sys(sp1 + 1);
        }
    }
    __syncthreads();

    // prefetched A-fragments of Hin for the upcoming P1
    u16x8 pAg0 = *(const u16x8*)&Hin[0][l15][l4 * 8];
    u16x8 pAg1 = *(const u16x8*)&Hin[0][l15][32 + l4 * 8];

    for (int t = 0; t < LW; ++t) {
        float hg[4];
        // ================= P1: GRU (A-input prefetched into pAg) =================
        {
            u16x8 Ah0 = *(const u16x8*)&hbf[l15][l4 * 8];
            u16x8 Ah1 = *(const u16x8*)&hbf[l15][32 + l4 * 8];
            f32x4 z4 = {0.f, 0.f, 0.f, 0.f};
            f32x4 aR = z4, aZ = z4, aNI = z4, aNH = z4;
            aR = mfma16(pAg0, Br[0], aR);  aR = mfma16(pAg1, Br[1], aR);
            aR = mfma16(Ah0, Br[2], aR);   aR = mfma16(Ah1, Br[3], aR);
            aZ = mfma16(pAg0, Bz[0], aZ);  aZ = mfma16(pAg1, Bz[1], aZ);
            aZ = mfma16(Ah0, Bz[2], aZ);   aZ = mfma16(Ah1, Bz[3], aZ);
            aNI = mfma16(pAg0, Bni[0], aNI); aNI = mfma16(pAg1, Bni[1], aNI);
            aNH = mfma16(Ah0, Bnh[0], aNH);  aNH = mfma16(Ah1, Bnh[1], aNH);
            #pragma unroll
            for (int j = 0; j < 4; ++j) {
                float r  = sigm(aR[j] + brs);
                float zz = sigm(aZ[j] + bzs);
                float nn = tanhfast(aNI[j] + bnis + r * (aNH[j] + bnhs));
                hg[j] = (1.0f - zz) * nn + zz * hreg[j];
            }
            if (l4 < 2) {
                #pragma unroll
                for (int j = 0; j < 4; ++j) se[l4 * 4 + j][o] = f2bf(hg[j]);
            }
        }
        bar_lgkm();   // P1e

        // ========== P2: bitonic sort — hybrid DPP(1,2)/swizzle(4,8,16)/shfl(32) ==========
        {
            float v0 = bf2f(se[2 * w][ln]);
            float v1 = bf2f(se[2 * w + 1][ln]);
            STG(2, 1)
            STG(4, 2)  STG(4, 1)
            STG(8, 4)  STG(8, 2)  STG(8, 1)
            STG(16, 8) STG(16, 4) STG(16, 2) STG(16, 1)
            STG(32, 16) STG(32, 8) STG(32, 4) STG(32, 2) STG(32, 1)
            STG(64, 32) STG(64, 16) STG(64, 8) STG(64, 4) STG(64, 2) STG(64, 1)
            se[8 + 2 * w][ln] = f2bf(v0);
            se[9 + 2 * w][ln] = f2bf(v1);
        }
        bar_lgkm();   // P2e

        // ====== P3: deferred per-wave flag publish (stores of step t-1 long acked) ======
        if (l < 7) {
            asm volatile("s_waitcnt vmcnt(0)" ::: "memory");
            if (ln == 0) st_sys(myflag + w, (unsigned)t);
        }
        // ================= P3: a1 = se @ W1^T, shuffle-write =================
        {
            u16x8 As0 = *(const u16x8*)&se[l15][l4 * 8];
            u16x8 As1 = *(const u16x8*)&se[l15][32 + l4 * 8];
            f32x4 c = {0.f, 0.f, 0.f, 0.f};
            c = mfma16(As0, B1f[0], c);
            c = mfma16(As1, B1f[1], c);
            #pragma unroll
            for (int j = 0; j < 4; ++j) {
                int m = l4 * 4 + j;            // p = m>>3 (se half), b = m&7
                int p = m >> 3, b = m & 7;
                int f = p * 64 + o;
                int q = (f & 31) * 4 + (f >> 5);
                a23[b * 4 + (q >> 5)][q & 31] = f2bf(c[j]);
            }
        }
        bar_lgkm();   // P3e

        // ============ P4/P5: waves 0,1 do a2+a3; waves 2,3 commit+prefetch ============
        if (w < 2) {
            const int Rb0 = 16 * w;
            u16x8 a2a = ld8_8al(&a23[Rb0 + l15][l4 * 8]);
            f32x4 z4 = {0.f, 0.f, 0.f, 0.f};
            f32x4 c2[2];
            c2[0] = mfma16(a2a, B2f[0], z4);
            c2[1] = mfma16(a2a, B2f[1], z4);
            #pragma unroll
            for (int nt = 0; nt < 2; ++nt)
                #pragma unroll
                for (int j = 0; j < 4; ++j) {
                    int m = Rb0 + l4 * 4 + j;
                    int b = m >> 2, i2 = m & 3;
                    int n = 16 * nt + l15;
                    int f2 = i2 * 32 + n;
                    int q2 = (f2 & 31) * 4 + (f2 >> 5);
                    a23[b * 4 + (q2 >> 5)][q2 & 31] = f2bf(c2[nt][j]);
                }
            asm volatile("s_waitcnt lgkmcnt(0)" ::: "memory");
            __builtin_amdgcn_sched_barrier(0);
            u16x8 a3a = ld8_8al(&a23[Rb0 + l15][l4 * 8]);
            f32x4 c3[2];
            c3[0] = mfma16(a3a, B3f[0], z4);
            c3[1] = mfma16(a3a, B3f[1], z4);
            #pragma unroll
            for (int nt = 0; nt < 2; ++nt)
                #pragma unroll
                for (int j = 0; j < 4; ++j) {
                    int m = Rb0 + l4 * 4 + j;
                    int b = m >> 2, i3 = m & 3;
                    int n = 16 * nt + l15;
                    w4A[b][i3 * 32 + n] = f2bf(fmaxf(c3[nt][j], 0.0f));
                }
        } else {
            const int rr = (tid - 128) >> 4, c4 = ((tid - 128) & 15) * 4;
            if (t + 1 < LW) {     // commit stash (slot t+1) -> Hin[(t+1)&1]
                u16x4 hv;
                if (l == 0) {
                    hv[0] = f2bf(stf.x); hv[1] = f2bf(stf.y);
                    hv[2] = f2bf(stf.z); hv[3] = f2bf(stf.w);
                } else {
                    u32x2v dv = {st0, st1};
                    hv = __builtin_bit_cast(u16x4, dv);
                }
                *(u16x4*)&Hin[(t + 1) & 1][rr][c4] = hv;
            }
            if (t + 2 < LW) {     // issue loads for slot t+2
                if (l == 0) {
                    stf = *(const float4*)(x + (size_t)(bb0 + rr) * 32768 + (t + 2) * 64 + c4);
                } else {
                    poll4(pflag, (unsigned)(t + 3));
                    const unsigned* sp = ring32
                        + ((size_t)((l - 1) * 8 + g) * D + ((t + 2) & (D - 1))) * 256
                        + rr * 32 + (c4 >> 1);
                    st0 = ld_sys(sp); st1 = ld_sys(sp + 1);
                }
            }
        }
        bar_lgkm();   // P5e
        if (bp && l > 0 && tid == 0)
            st_sys(myccnt, (unsigned)(t + 2));   // slots <= t+1 consumed

        // ================= P6: scores + h update + publish =================
        {
            u16x8 A40 = *(const u16x8*)&w4A[l15][l4 * 8];
            u16x8 A41 = *(const u16x8*)&w4A[l15][32 + l4 * 8];
            u16x8 A42 = *(const u16x8*)&w4A[l15][64 + l4 * 8];
            u16x8 A43 = *(const u16x8*)&w4A[l15][96 + l4 * 8];
            // prefetch next step's input fragments (committed at P4, stable after P5e)
            pAg0 = *(const u16x8*)&Hin[(t + 1) & 1][l15][l4 * 8];
            pAg1 = *(const u16x8*)&Hin[(t + 1) & 1][l15][32 + l4 * 8];
            f32x4 cs = {0.f, 0.f, 0.f, 0.f};
            cs = mfma16(A40, B4f[0], cs);
            cs = mfma16(A41, B4f[1], cs);
            cs = mfma16(A42, B4f[2], cs);
            cs = mfma16(A43, B4f[3], cs);

            if (bp && l < 7 && t >= D) {   // ring back-pressure (shallow ring only)
                poll_ge(nccnt, (unsigned)(t - D + 1));
            }
            unsigned* slotp = ring32 + ((size_t)(l * 8 + g) * D + (t & (D - 1))) * 256;
            float hn[4]; u16 hb[4];
            #pragma unroll
            for (int j = 0; j < 4; ++j) {
                hn[j] = hg[j] * sigm(cs[j]);
                hreg[j] = hn[j];
                hb[j] = f2bf(hn[j]);
            }
            if (l4 < 2) {
                #pragma unroll
                for (int j = 0; j < 4; ++j) {
                    int row = l4 * 4 + j;
                    hbf[row][o] = hb[j];
                    if (l == 7) ys[(((size_t)(bb0 + row) << 9) + t) * 64 + o] = hn[j];
                    if (t == 511) hfin[((l << 6) + bb0 + row) * 64 + o] = hn[j];
                }
            }
            if (l < 7) {
                #pragma unroll
                for (int j = 0; j < 4; ++j) {
                    unsigned ob = (unsigned)__shfl_xor((int)(unsigned)hb[j], 1) & 0xffffu;
                    if (l4 < 2 && !(l15 & 1)) {
                        unsigned word = (unsigned)hb[j] | (ob << 16);
                        st_sys(&slotp[(l4 * 4 + j) * 32 + (o >> 1)], word);
                    }
                }
            }
        }
        bar_lgkm();   // P6e (lgkm only; ring stores drain in background)
    }

    // epilogue: final flag so consumer's last prefetches can complete
    if (l < 7) {
        asm volatile("s_waitcnt vmcnt(0)" ::: "memory");
        if (ln == 0) st_sys(myflag + w, 512u);
    }
}

// ---------------- heads: per-window seg + cls logits ----------------
__global__ __launch_bounds__(256) void heads_kernel(
    const float* __restrict__ ys,
    const float* __restrict__ sw1, const float* __restrict__ sb1,
    const float* __restrict__ sw2, const float* __restrict__ sb2,
    const float* __restrict__ sw3, const float* __restrict__ sb3,
    const float* __restrict__ sw4, const float* __restrict__ sb4,
    const float* __restrict__ cw1, const float* __restrict__ cb1,
    const float* __restrict__ cw2, const float* __restrict__ cb2,
    const float* __restrict__ cw3, const float* __restrict__ cb3,
    const float* __restrict__ cw4, const float* __restrict__ cb4,
    float* __restrict__ seg_out, float* __restrict__ cls_tmp)
{
    const int idx = blockIdx.x * 256 + threadIdx.x;
    if (idx >= 64 * LW) return;
    const int b = idx >> 9, t = idx & 511;

    float y[64];
    const float4* yp = (const float4*)(ys + (size_t)idx * 64);
    #pragma unroll
    for (int i = 0; i < 16; ++i) {
        float4 v = yp[i];
        y[4 * i + 0] = v.x; y[4 * i + 1] = v.y; y[4 * i + 2] = v.z; y[4 * i + 3] = v.w;
    }

    float t1[8][4], t2[8][4], t3[8][4];

    // ======== seg head ========
    #pragma unroll
    for (int g = 0; g < 8; ++g)
        #pragma unroll
        for (int s = 0; s < 4; ++s) {
            float acc = sb1[s];
            #pragma unroll
            for (int k = 0; k < 8; ++k) acc = fmaf(y[g * 8 + k], sw1[s * 8 + k], acc);
            t1[g][s] = acc;
        }
    #pragma unroll
    for (int i = 0; i < 8; ++i) {
        float sh[4];
        #pragma unroll
        for (int j = 0; j < 4; ++j) { int m = i * 4 + j; sh[j] = t1[m & 7][m >> 3]; }
        #pragma unroll
        for (int s = 0; s < 4; ++s) {
            float acc = sb2[s];
            #pragma unroll
            for (int j = 0; j < 4; ++j) acc = fmaf(sh[j], sw2[s * 4 + j], acc);
            t2[i][s] = acc;
        }
    }
    #pragma unroll
    for (int i = 0; i < 8; ++i) {
        float sh[4];
        #pragma unroll
        for (int j = 0; j < 4; ++j) { int m = i * 4 + j; sh[j] = t2[m & 7][m >> 3]; }
        #pragma unroll
        for (int s = 0; s < 4; ++s) {
            float acc = sb3[s];
            #pragma unroll
            for (int j = 0; j < 4; ++j) acc = fmaf(sh[j], sw3[s * 4 + j], acc);
            t3[i][s] = acc;
        }
    }
    #pragma unroll
    for (int w = 0; w < 16; ++w) {
        float o4[4];
        #pragma unroll
        for (int s = 0; s < 4; ++s) {
            float acc = sb4[w];
            #pragma unroll
            for (int j = 0; j < 8; ++j) {
                int f = s * 8 + j;
                acc = fmaf(t3[f >> 2][f & 3], sw4[w * 8 + j], acc);
            }
            o4[s] = acc;
        }
        float4 vv = {o4[0], o4[1], o4[2], o4[3]};
        ((float4*)seg_out)[b * 8192 + t * 16 + w] = vv;
    }

    // ======== cls head ========
    #pragma unroll
    for (int g = 0; g < 8; ++g)
        #pragma unroll
        for (int s = 0; s < 4; ++s) {
            float acc = cb1[s];
            #pragma unroll
            for (int k = 0; k < 8; ++k) acc = fmaf(y[g * 8 + k], cw1[s * 8 + k], acc);
            t1[g][s] = acc;
        }
    #pragma unroll
    for (int i = 0; i < 8; ++i) {
        float sh[4];
        #pragma unroll
        for (int j = 0; j < 4; ++j) { int m = i * 4 + j; sh[j] = t1[m & 7][m >> 3]; }
        #pragma unroll
        for (int s = 0; s < 4; ++s) {
            float acc = cb2[s];
            #pragma unroll
            for (int j = 0; j < 4; ++j) acc = fmaf(sh[j], cw2[s * 4 + j], acc);
            t2[i][s] = acc;
        }
    }
    #pragma unroll
    for (int i = 0; i < 8; ++i) {
        float sh[4];
        #pragma unroll
        for (int j = 0; j < 4; ++j) { int m = i * 4 + j; sh[j] = t2[m & 7][m >> 3]; }
        #pragma unroll
        for (int s = 0; s < 4; ++s) {
            float acc = cb3[s];
            #pragma unroll
            for (int j = 0; j < 4; ++j) acc = fmaf(sh[j], cw3[s * 4 + j], acc);
            t3[i][s] = fmaxf(acc, 0.f);
        }
    }
    float cc[4];
    #pragma unroll
    for (int c = 0; c < 4; ++c) {
        float acc = cb4[c];
        #pragma unroll
        for (int k = 0; k < 32; ++k)
            acc = fmaf(t3[k >> 2][k & 3], cw4[c * 32 + k], acc);
        cc[c] = acc;
    }
    float4 cv = {cc[0], cc[1], cc[2], cc[3]};
    ((float4*)cls_tmp)[idx] = cv;
}

// ---------------- cls mean over windows ----------------
__global__ __launch_bounds__(256) void cls_reduce_kernel(
    const float* __restrict__ cls_tmp, float* __restrict__ cls_out)
{
    const int tid = threadIdx.x;
    const int b = tid >> 2, q = tid & 3;
    float ax = 0.f, ay = 0.f, az = 0.f, aw = 0.f;
    for (int t = q; t < 512; t += 4) {
        float4 v = ((const float4*)cls_tmp)[b * 512 + t];
        ax += v.x; ay += v.y; az += v.z; aw += v.w;
    }
    ax += __shfl_xor(ax, 1); ay += __shfl_xor(ay, 1);
    az += __shfl_xor(az, 1); aw += __shfl_xor(aw, 1);
    ax += __shfl_xor(ax, 2); ay += __shfl_xor(ay, 2);
    az += __shfl_xor(az, 2); aw += __shfl_xor(aw, 2);
    if (q == 0) {
        float4 rv = {ax / 512.f, ay / 512.f, az / 512.f, aw / 512.f};
        ((float4*)cls_out)[b] = rv;
    }
}

// ---------------- avg_pool1d(k=11,s=1) with 10 zero history ----------------
__global__ __launch_bounds__(256) void pool_kernel(
    const float* __restrict__ seg, float* __restrict__ pool_out)
{
    const int idx = blockIdx.x * 256 + threadIdx.x;
    if (idx >= 64 * 8192) return;
    const int b = idx >> 13, ll = idx & 8191;
    float ax = 0.f, ay = 0.f, az = 0.f, aw = 0.f;
    int j0 = ll - 10; if (j0 < 0) j0 = 0;
    for (int j = j0; j <= ll; ++j) {
        float4 v = ((const float4*)seg)[b * 8192 + j];
        ax += v.x; ay += v.y; az += v.z; aw += v.w;
    }
    const float inv = 1.0f / 11.0f;
    float4 ov = {ax * inv, ay * inv, az * inv, aw * inv};
    ((float4*)pool_out)[idx] = ov;
}

extern "C" void kernel_launch(void* const* d_in, const int* in_sizes, int n_in,
                              void* d_out, int out_size, void* d_ws, size_t ws_size,
                              hipStream_t stream)
{
    const float* x    = (const float*)d_in[0];
    const float* h0   = (const float*)d_in[1];
    const float* w_ih = (const float*)d_in[2];
    const float* w_hh = (const float*)d_in[3];
    const float* bihp = (const float*)d_in[4];
    const float* bhhp = (const float*)d_in[5];
    const float* aw1  = (const float*)d_in[6];
    const float* aw2  = (const float*)d_in[7];
    const float* aw3  = (const float*)d_in[8];
    const float* aw4  = (const float*)d_in[9];
    const float* sw1  = (const float*)d_in[10];
    const float* sb1  = (const float*)d_in[11];
    const float* sw2  = (const float*)d_in[12];
    const float* sb2  = (const float*)d_in[13];
    const float* sw3  = (const float*)d_in[14];
    const float* sb3  = (const float*)d_in[15];
    const float* sw4  = (const float*)d_in[16];
    const float* sb4  = (const float*)d_in[17];
    const float* cw1  = (const float*)d_in[18];
    const float* cb1  = (const float*)d_in[19];
    const float* cw2  = (const float*)d_in[20];
    const float* cb2  = (const float*)d_in[21];
    const float* cw3  = (const float*)d_in[22];
    const float* cb3  = (const float*)d_in[23];
    const float* cw4  = (const float*)d_in[24];
    const float* cb4  = (const float*)d_in[25];

    float* out      = (float*)d_out;
    float* pool_out = out;                 // (64,8192,4)
    float* cls_out  = out + 2097152;       // (64,4)
    float* ys_out   = out + 2097408;       // (64,512,64)
    float* hfin     = out + 4194560;       // (8,64,64)
    float* seg_out  = out + 4227328;       // (64,8192,4)
    float* cls_tmp  = pool_out;            // staged in pool region, overwritten last

    unsigned* flags  = (unsigned*)d_ws;                   // 32 KB header
    unsigned* ring32 = (unsigned*)((char*)d_ws + 32768);  // 56 x D x 256 u32

    // ring depth: unique slot per timestep if ws allows (no back-pressure)
    size_t slots = (ws_size > 32768) ? (ws_size - 32768) / (56ull * 256 * 4) : 8;
    int D = 512;
    if (slots < 512) {
        D = 8;
        while ((size_t)(D * 2) <= slots && D < 512) D <<= 1;
    }

    init_flags<<<32, 256, 0, stream>>>(flags);
    rnn_kernel<<<64, 256, 0, stream>>>(x, h0, w_ih, w_hh, bihp, bhhp,
                                       aw1, aw2, aw3, aw4, ys_out, hfin,
                                       flags, ring32, D);
    heads_kernel<<<128, 256, 0, stream>>>(ys_out, sw1, sb1, sw2, sb2, sw3, sb3, sw4, sb4,
                                          cw1, cb1, cw2, cb2, cw3, cb3, cw4, cb4,
                                          seg_out, cls_tmp);
    cls_reduce_kernel<<<1, 256, 0, stream>>>(cls_tmp, cls_out);
    pool_kernel<<<2048, 256, 0, stream>>>(seg_out, pool_out);
}

// Round 11
// 1350.446 us; speedup vs baseline: 6.1006x; 1.0023x over previous
//
#include <hip/hip_runtime.h>
#include <math.h>

#define LW  512

typedef unsigned short u16;
typedef float f32x4 __attribute__((ext_vector_type(4)));
typedef u16 u16x4 __attribute__((ext_vector_type(4)));
typedef u16 u16x8 __attribute__((ext_vector_type(8)));
typedef unsigned u32x2v __attribute__((ext_vector_type(2)));
typedef __bf16 bf16x8 __attribute__((ext_vector_type(8)));

__device__ __forceinline__ u16 f2bf(float f) {
    return __builtin_bit_cast(u16, (__bf16)f);   // native RNE convert (single-variable test)
}
__device__ __forceinline__ float bf2f(u16 h) {
    unsigned u = ((unsigned)h) << 16;
    return __builtin_bit_cast(float, u);
}
__device__ __forceinline__ float sigm(float x) {
    return __builtin_amdgcn_rcpf(1.0f + __expf(-x));
}
__device__ __forceinline__ float tanhfast(float x) {
    return 1.0f - 2.0f * __builtin_amdgcn_rcpf(1.0f + __expf(2.0f * x));
}
__device__ __forceinline__ f32x4 mfma16(u16x8 a, u16x8 b, f32x4 c) {
    return __builtin_amdgcn_mfma_f32_16x16x32_bf16(
        __builtin_bit_cast(bf16x8, a), __builtin_bit_cast(bf16x8, b), c, 0, 0, 0);
}
__device__ __forceinline__ u16x8 ld8_8al(const u16* p) {   // 8B-aligned 16B load
    u16x4 lo = *(const u16x4*)p;
    u16x4 hi = *(const u16x4*)(p + 4);
    return __builtin_shufflevector(lo, hi, 0, 1, 2, 3, 4, 5, 6, 7);
}
__device__ __forceinline__ unsigned ld_sys(const unsigned* p) {
    return __hip_atomic_load(p, __ATOMIC_RELAXED, __HIP_MEMORY_SCOPE_SYSTEM);
}
__device__ __forceinline__ void st_sys(unsigned* p, unsigned v) {
    __hip_atomic_store(p, v, __ATOMIC_RELAXED, __HIP_MEMORY_SCOPE_SYSTEM);
}
__device__ __forceinline__ void poll_ge(const unsigned* p, unsigned want) {
    while (ld_sys(p) < want) __builtin_amdgcn_s_sleep(2);
    asm volatile("" ::: "memory");
    __builtin_amdgcn_sched_barrier(0);
}
__device__ __forceinline__ void poll4(const unsigned* p, unsigned want) {
    for (;;) {
        unsigned m0 = ld_sys(p + 0), m1 = ld_sys(p + 1);
        unsigned m2 = ld_sys(p + 2), m3 = ld_sys(p + 3);
        unsigned a = m0 < m1 ? m0 : m1;
        unsigned b = m2 < m3 ? m2 : m3;
        if ((a < b ? a : b) >= want) break;
        __builtin_amdgcn_s_sleep(2);
    }
    asm volatile("" ::: "memory");
    __builtin_amdgcn_sched_barrier(0);
}
__device__ __forceinline__ void bar_lgkm() {
    asm volatile("s_waitcnt lgkmcnt(0)" ::: "memory");
    __builtin_amdgcn_s_barrier();
}

// ---- sort lane exchanges (R9-PROVEN set; permlane PERMANENTLY abandoned:
// R5/R6/R7/R10 all failed bit-identically with any permlane16/32_swap form) ----
// J=1,2: single quad_perm mov_dpp. J=4,8,16: ds_swizzle bit-mode. J=32: __shfl_xor.
template<int CTRL> __device__ __forceinline__ float dppf(float v) {
    return __builtin_bit_cast(float,
        __builtin_amdgcn_mov_dpp(__builtin_bit_cast(int, v), CTRL, 0xF, 0xF, false));
}
template<int OFF> __device__ __forceinline__ float swzf(float v) {
    return __builtin_bit_cast(float,
        __builtin_amdgcn_ds_swizzle(__builtin_bit_cast(int, v), OFF));
}
template<int J> __device__ __forceinline__ float xch(float v) {
    if constexpr (J == 1)  return dppf<0xB1>(v);        // quad_perm [1,0,3,2]
    else if constexpr (J == 2)  return dppf<0x4E>(v);   // quad_perm [2,3,0,1]
    else if constexpr (J == 4)  return swzf<0x101F>(v); // bit-mode xor4
    else if constexpr (J == 8)  return swzf<0x201F>(v); // bit-mode xor8
    else if constexpr (J == 16) return swzf<0x401F>(v); // bit-mode xor16
    else return __shfl_xor(v, 32);
}
#define STG(KK, J) { \
    float o0 = xch<J>(v0), o1 = xch<J>(v1); \
    bool keepmin = (((ln & KK) == 0) == ((ln & J) == 0)); \
    v0 = keepmin ? fminf(v0, o0) : fmaxf(v0, o0); \
    v1 = keepmin ? fminf(v1, o1) : fmaxf(v1, o1); }

// zero counters
__global__ __launch_bounds__(256) void init_flags(unsigned* f) {
    f[blockIdx.x * 256 + threadIdx.x] = 0u;
}

// ---------------- recurrence: (layer, batch-group) per block ----------------
// R9-proven structure. Single change vs R9: native bf16 convert in f2bf.
__global__ __launch_bounds__(256, 1) void rnn_kernel(
    const float* __restrict__ x, const float* __restrict__ h0,
    const float* __restrict__ w_ih, const float* __restrict__ w_hh,
    const float* __restrict__ bih, const float* __restrict__ bhh,
    const float* __restrict__ aw1, const float* __restrict__ aw2,
    const float* __restrict__ aw3, const float* __restrict__ aw4,
    float* __restrict__ ys, float* __restrict__ hfin,
    unsigned* __restrict__ flags, unsigned* __restrict__ ring32, int D)
{
    const int l   = blockIdx.x >> 3;   // layer 0..7
    const int g   = blockIdx.x & 7;    // batch group 0..7
    const int bb0 = g * 8;
    const int tid = threadIdx.x;
    const int w   = tid >> 6;          // wave 0..3
    const int ln  = tid & 63;
    const int l15 = ln & 15;
    const int l4  = ln >> 4;
    const bool bp = (D < LW);          // back-pressure only for shallow ring

    unsigned* myflag = flags + (size_t)(l * 8 + g) * 32;         // [4] per-wave
    unsigned* pflag  = flags + (size_t)((l - 1) * 8 + g) * 32;   // producer's [4]
    unsigned* myccnt = flags + 4096 + (size_t)(l * 8 + g) * 32;
    unsigned* nccnt  = flags + 4096 + (size_t)((l + 1) * 8 + g) * 32;

    __shared__ __align__(16) u16 Hin[2][16][72]; // dbl-buffered layer input, rows 8..15 zero
    __shared__ __align__(16) u16 hbf[16][72];    // h state (bf16), rows 8..15 zero
    __shared__ __align__(16) u16 se [16][72];    // rows 0..7 = h, 8..15 = sorted h
    __shared__ __align__(16) u16 a23[32][36];    // a1-shuffled / a2-shuffled overlay
    __shared__ __align__(16) u16 w4A[16][136];   // relu(a3) flat 128, rows 8..15 zero

    for (int i = tid; i < 16 * 72; i += 256) {
        int r = i / 72, c = i % 72;
        if (r >= 8) { Hin[0][r][c] = 0; Hin[1][r][c] = 0; hbf[r][c] = 0; }
    }
    for (int i = tid; i < 16 * 136; i += 256) {
        int r = i / 136;
        if (r >= 8) w4A[r][i % 136] = 0;
    }

    // ---- weight B-fragments into VGPRs (t-invariant) ----
    const int o = 16 * w + l15;
    auto ldw8 = [](const float* p) {
        float4 v0 = *(const float4*)p;
        float4 v1 = *(const float4*)(p + 4);
        u16x8 r;
        r[0] = f2bf(v0.x); r[1] = f2bf(v0.y); r[2] = f2bf(v0.z); r[3] = f2bf(v0.w);
        r[4] = f2bf(v1.x); r[5] = f2bf(v1.y); r[6] = f2bf(v1.z); r[7] = f2bf(v1.w);
        return r;
    };
    const float* ih = w_ih + l * 12288;
    const float* hh = w_hh + l * 12288;
    u16x8 Br[4], Bz[4], Bni[2], Bnh[2], B1f[2], B2f[2], B3f[2], B4f[4];
    Br[0] = ldw8(ih + o * 64 + l4 * 8);        Br[1] = ldw8(ih + o * 64 + 32 + l4 * 8);
    Br[2] = ldw8(hh + o * 64 + l4 * 8);        Br[3] = ldw8(hh + o * 64 + 32 + l4 * 8);
    Bz[0] = ldw8(ih + (64 + o) * 64 + l4 * 8); Bz[1] = ldw8(ih + (64 + o) * 64 + 32 + l4 * 8);
    Bz[2] = ldw8(hh + (64 + o) * 64 + l4 * 8); Bz[3] = ldw8(hh + (64 + o) * 64 + 32 + l4 * 8);
    Bni[0] = ldw8(ih + (128 + o) * 64 + l4 * 8); Bni[1] = ldw8(ih + (128 + o) * 64 + 32 + l4 * 8);
    Bnh[0] = ldw8(hh + (128 + o) * 64 + l4 * 8); Bnh[1] = ldw8(hh + (128 + o) * 64 + 32 + l4 * 8);
    B1f[0] = ldw8(aw1 + l * 4096 + o * 64 + l4 * 8);
    B1f[1] = ldw8(aw1 + l * 4096 + o * 64 + 32 + l4 * 8);
    B2f[0] = ldw8(aw2 + l * 1024 + l15 * 32 + l4 * 8);
    B2f[1] = ldw8(aw2 + l * 1024 + (16 + l15) * 32 + l4 * 8);
    B3f[0] = ldw8(aw3 + l * 1024 + l15 * 32 + l4 * 8);
    B3f[1] = ldw8(aw3 + l * 1024 + (16 + l15) * 32 + l4 * 8);
    #pragma unroll
    for (int kk = 0; kk < 4; ++kk)
        B4f[kk] = ldw8(aw4 + l * 8192 + o * 128 + kk * 32 + l4 * 8);

    const float brs  = bih[l * 192 + o]       + bhh[l * 192 + o];
    const float bzs  = bih[l * 192 + 64 + o]  + bhh[l * 192 + 64 + o];
    const float bnis = bih[l * 192 + 128 + o];
    const float bnhs = bhh[l * 192 + 128 + o];

    float hreg[4];
    {
        float hv = h0[l * 64 + o];
        #pragma unroll
        for (int j = 0; j < 4; ++j) hreg[j] = hv;
        if (l4 < 2) {
            u16 hb = f2bf(hv);
            #pragma unroll
            for (int j = 0; j < 4; ++j) hbf[l4 * 4 + j][o] = hb;
        }
    }

    // ---- prologue: stage slot 0 into Hin[0]; slot 1 into stash regs ----
    float4 stf = {0.f, 0.f, 0.f, 0.f};
    unsigned st0 = 0, st1 = 0;
    if (w >= 2) {
        const int rr = (tid - 128) >> 4, c4 = ((tid - 128) & 15) * 4;
        if (l == 0) {
            float4 a = *(const float4*)(x + (size_t)(bb0 + rr) * 32768 + c4);
            u16x4 hv;
            hv[0] = f2bf(a.x); hv[1] = f2bf(a.y); hv[2] = f2bf(a.z); hv[3] = f2bf(a.w);
            *(u16x4*)&Hin[0][rr][c4] = hv;
            stf = *(const float4*)(x + (size_t)(bb0 + rr) * 32768 + 64 + c4);
        } else {
            poll4(pflag, 1u);
            const unsigned* sp0 = ring32 + ((size_t)((l - 1) * 8 + g) * D + 0) * 256 + rr * 32 + (c4 >> 1);
            unsigned a0 = ld_sys(sp0), a1 = ld_sys(sp0 + 1);
            u32x2v dv = {a0, a1};
            *(u16x4*)&Hin[0][rr][c4] = __builtin_bit_cast(u16x4, dv);
            poll4(pflag, 2u);
            const unsigned* sp1 = ring32 + ((size_t)((l - 1) * 8 + g) * D + 1) * 256 + rr * 32 + (c4 >> 1);
            st0 = ld_sys(sp1); st1 = ld_sys(sp1 + 1);
        }
    }
    __syncthreads();

    // prefetched A-fragments of Hin for the upcoming P1
    u16x8 pAg0 = *(const u16x8*)&Hin[0][l15][l4 * 8];
    u16x8 pAg1 = *(const u16x8*)&Hin[0][l15][32 + l4 * 8];

    for (int t = 0; t < LW; ++t) {
        float hg[4];
        // ================= P1: GRU (A-input prefetched into pAg) =================
        {
            u16x8 Ah0 = *(const u16x8*)&hbf[l15][l4 * 8];
            u16x8 Ah1 = *(const u16x8*)&hbf[l15][32 + l4 * 8];
            f32x4 z4 = {0.f, 0.f, 0.f, 0.f};
            f32x4 aR = z4, aZ = z4, aNI = z4, aNH = z4;
            aR = mfma16(pAg0, Br[0], aR);  aR = mfma16(pAg1, Br[1], aR);
            aR = mfma16(Ah0, Br[2], aR);   aR = mfma16(Ah1, Br[3], aR);
            aZ = mfma16(pAg0, Bz[0], aZ);  aZ = mfma16(pAg1, Bz[1], aZ);
            aZ = mfma16(Ah0, Bz[2], aZ);   aZ = mfma16(Ah1, Bz[3], aZ);
            aNI = mfma16(pAg0, Bni[0], aNI); aNI = mfma16(pAg1, Bni[1], aNI);
            aNH = mfma16(Ah0, Bnh[0], aNH);  aNH = mfma16(Ah1, Bnh[1], aNH);
            #pragma unroll
            for (int j = 0; j < 4; ++j) {
                float r  = sigm(aR[j] + brs);
                float zz = sigm(aZ[j] + bzs);
                float nn = tanhfast(aNI[j] + bnis + r * (aNH[j] + bnhs));
                hg[j] = (1.0f - zz) * nn + zz * hreg[j];
            }
            if (l4 < 2) {
                #pragma unroll
                for (int j = 0; j < 4; ++j) se[l4 * 4 + j][o] = f2bf(hg[j]);
            }
        }
        bar_lgkm();   // P1e

        // ========== P2: bitonic sort — hybrid DPP(1,2)/swizzle(4,8,16)/shfl(32) ==========
        {
            float v0 = bf2f(se[2 * w][ln]);
            float v1 = bf2f(se[2 * w + 1][ln]);
            STG(2, 1)
            STG(4, 2)  STG(4, 1)
            STG(8, 4)  STG(8, 2)  STG(8, 1)
            STG(16, 8) STG(16, 4) STG(16, 2) STG(16, 1)
            STG(32, 16) STG(32, 8) STG(32, 4) STG(32, 2) STG(32, 1)
            STG(64, 32) STG(64, 16) STG(64, 8) STG(64, 4) STG(64, 2) STG(64, 1)
            se[8 + 2 * w][ln] = f2bf(v0);
            se[9 + 2 * w][ln] = f2bf(v1);
        }
        bar_lgkm();   // P2e

        // ====== P3: deferred per-wave flag publish (stores of step t-1 long acked) ======
        if (l < 7) {
            asm volatile("s_waitcnt vmcnt(0)" ::: "memory");
            if (ln == 0) st_sys(myflag + w, (unsigned)t);
        }
        // ================= P3: a1 = se @ W1^T, shuffle-write =================
        {
            u16x8 As0 = *(const u16x8*)&se[l15][l4 * 8];
            u16x8 As1 = *(const u16x8*)&se[l15][32 + l4 * 8];
            f32x4 c = {0.f, 0.f, 0.f, 0.f};
            c = mfma16(As0, B1f[0], c);
            c = mfma16(As1, B1f[1], c);
            #pragma unroll
            for (int j = 0; j < 4; ++j) {
                int m = l4 * 4 + j;            // p = m>>3 (se half), b = m&7
                int p = m >> 3, b = m & 7;
                int f = p * 64 + o;
                int q = (f & 31) * 4 + (f >> 5);
                a23[b * 4 + (q >> 5)][q & 31] = f2bf(c[j]);
            }
        }
        bar_lgkm();   // P3e

        // ============ P4/P5: waves 0,1 do a2+a3; waves 2,3 commit+prefetch ============
        if (w < 2) {
            const int Rb0 = 16 * w;
            u16x8 a2a = ld8_8al(&a23[Rb0 + l15][l4 * 8]);
            f32x4 z4 = {0.f, 0.f, 0.f, 0.f};
            f32x4 c2[2];
            c2[0] = mfma16(a2a, B2f[0], z4);
            c2[1] = mfma16(a2a, B2f[1], z4);
            #pragma unroll
            for (int nt = 0; nt < 2; ++nt)
                #pragma unroll
                for (int j = 0; j < 4; ++j) {
                    int m = Rb0 + l4 * 4 + j;
                    int b = m >> 2, i2 = m & 3;
                    int n = 16 * nt + l15;
                    int f2 = i2 * 32 + n;
                    int q2 = (f2 & 31) * 4 + (f2 >> 5);
                    a23[b * 4 + (q2 >> 5)][q2 & 31] = f2bf(c2[nt][j]);
                }
            asm volatile("s_waitcnt lgkmcnt(0)" ::: "memory");
            __builtin_amdgcn_sched_barrier(0);
            u16x8 a3a = ld8_8al(&a23[Rb0 + l15][l4 * 8]);
            f32x4 c3[2];
            c3[0] = mfma16(a3a, B3f[0], z4);
            c3[1] = mfma16(a3a, B3f[1], z4);
            #pragma unroll
            for (int nt = 0; nt < 2; ++nt)
                #pragma unroll
                for (int j = 0; j < 4; ++j) {
                    int m = Rb0 + l4 * 4 + j;
                    int b = m >> 2, i3 = m & 3;
                    int n = 16 * nt + l15;
                    w4A[b][i3 * 32 + n] = f2bf(fmaxf(c3[nt][j], 0.0f));
                }
        } else {
            const int rr = (tid - 128) >> 4, c4 = ((tid - 128) & 15) * 4;
            if (t + 1 < LW) {     // commit stash (slot t+1) -> Hin[(t+1)&1]
                u16x4 hv;
                if (l == 0) {
                    hv[0] = f2bf(stf.x); hv[1] = f2bf(stf.y);
                    hv[2] = f2bf(stf.z); hv[3] = f2bf(stf.w);
                } else {
                    u32x2v dv = {st0, st1};
                    hv = __builtin_bit_cast(u16x4, dv);
                }
                *(u16x4*)&Hin[(t + 1) & 1][rr][c4] = hv;
            }
            if (t + 2 < LW) {     // issue loads for slot t+2
                if (l == 0) {
                    stf = *(const float4*)(x + (size_t)(bb0 + rr) * 32768 + (t + 2) * 64 + c4);
                } else {
                    poll4(pflag, (unsigned)(t + 3));
                    const unsigned* sp = ring32
                        + ((size_t)((l - 1) * 8 + g) * D + ((t + 2) & (D - 1))) * 256
                        + rr * 32 + (c4 >> 1);
                    st0 = ld_sys(sp); st1 = ld_sys(sp + 1);
                }
            }
        }
        bar_lgkm();   // P5e
        if (bp && l > 0 && tid == 0)
            st_sys(myccnt, (unsigned)(t + 2));   // slots <= t+1 consumed

        // ================= P6: scores + h update + publish =================
        {
            u16x8 A40 = *(const u16x8*)&w4A[l15][l4 * 8];
            u16x8 A41 = *(const u16x8*)&w4A[l15][32 + l4 * 8];
            u16x8 A42 = *(const u16x8*)&w4A[l15][64 + l4 * 8];
            u16x8 A43 = *(const u16x8*)&w4A[l15][96 + l4 * 8];
            // prefetch next step's input fragments (committed at P4, stable after P5e)
            pAg0 = *(const u16x8*)&Hin[(t + 1) & 1][l15][l4 * 8];
            pAg1 = *(const u16x8*)&Hin[(t + 1) & 1][l15][32 + l4 * 8];
            f32x4 cs = {0.f, 0.f, 0.f, 0.f};
            cs = mfma16(A40, B4f[0], cs);
            cs = mfma16(A41, B4f[1], cs);
            cs = mfma16(A42, B4f[2], cs);
            cs = mfma16(A43, B4f[3], cs);

            if (bp && l < 7 && t >= D) {   // ring back-pressure (shallow ring only)
                poll_ge(nccnt, (unsigned)(t - D + 1));
            }
            unsigned* slotp = ring32 + ((size_t)(l * 8 + g) * D + (t & (D - 1))) * 256;
            float hn[4]; u16 hb[4];
            #pragma unroll
            for (int j = 0; j < 4; ++j) {
                hn[j] = hg[j] * sigm(cs[j]);
                hreg[j] = hn[j];
                hb[j] = f2bf(hn[j]);
            }
            if (l4 < 2) {
                #pragma unroll
                for (int j = 0; j < 4; ++j) {
                    int row = l4 * 4 + j;
                    hbf[row][o] = hb[j];
                    if (l == 7) ys[(((size_t)(bb0 + row) << 9) + t) * 64 + o] = hn[j];
                    if (t == 511) hfin[((l << 6) + bb0 + row) * 64 + o] = hn[j];
                }
            }
            if (l < 7) {
                #pragma unroll
                for (int j = 0; j < 4; ++j) {
                    unsigned ob = (unsigned)__shfl_xor((int)(unsigned)hb[j], 1) & 0xffffu;
                    if (l4 < 2 && !(l15 & 1)) {
                        unsigned word = (unsigned)hb[j] | (ob << 16);
                        st_sys(&slotp[(l4 * 4 + j) * 32 + (o >> 1)], word);
                    }
                }
            }
        }
        bar_lgkm();   // P6e (lgkm only; ring stores drain in background)
    }

    // epilogue: final flag so consumer's last prefetches can complete
    if (l < 7) {
        asm volatile("s_waitcnt vmcnt(0)" ::: "memory");
        if (ln == 0) st_sys(myflag + w, 512u);
    }
}

// ---------------- heads: per-window seg + cls logits ----------------
__global__ __launch_bounds__(256) void heads_kernel(
    const float* __restrict__ ys,
    const float* __restrict__ sw1, const float* __restrict__ sb1,
    const float* __restrict__ sw2, const float* __restrict__ sb2,
    const float* __restrict__ sw3, const float* __restrict__ sb3,
    const float* __restrict__ sw4, const float* __restrict__ sb4,
    const float* __restrict__ cw1, const float* __restrict__ cb1,
    const float* __restrict__ cw2, const float* __restrict__ cb2,
    const float* __restrict__ cw3, const float* __restrict__ cb3,
    const float* __restrict__ cw4, const float* __restrict__ cb4,
    float* __restrict__ seg_out, float* __restrict__ cls_tmp)
{
    const int idx = blockIdx.x * 256 + threadIdx.x;
    if (idx >= 64 * LW) return;
    const int b = idx >> 9, t = idx & 511;

    float y[64];
    const float4* yp = (const float4*)(ys + (size_t)idx * 64);
    #pragma unroll
    for (int i = 0; i < 16; ++i) {
        float4 v = yp[i];
        y[4 * i + 0] = v.x; y[4 * i + 1] = v.y; y[4 * i + 2] = v.z; y[4 * i + 3] = v.w;
    }

    float t1[8][4], t2[8][4], t3[8][4];

    // ======== seg head ========
    #pragma unroll
    for (int g = 0; g < 8; ++g)
        #pragma unroll
        for (int s = 0; s < 4; ++s) {
            float acc = sb1[s];
            #pragma unroll
            for (int k = 0; k < 8; ++k) acc = fmaf(y[g * 8 + k], sw1[s * 8 + k], acc);
            t1[g][s] = acc;
        }
    #pragma unroll
    for (int i = 0; i < 8; ++i) {
        float sh[4];
        #pragma unroll
        for (int j = 0; j < 4; ++j) { int m = i * 4 + j; sh[j] = t1[m & 7][m >> 3]; }
        #pragma unroll
        for (int s = 0; s < 4; ++s) {
            float acc = sb2[s];
            #pragma unroll
            for (int j = 0; j < 4; ++j) acc = fmaf(sh[j], sw2[s * 4 + j], acc);
            t2[i][s] = acc;
        }
    }
    #pragma unroll
    for (int i = 0; i < 8; ++i) {
        float sh[4];
        #pragma unroll
        for (int j = 0; j < 4; ++j) { int m = i * 4 + j; sh[j] = t2[m & 7][m >> 3]; }
        #pragma unroll
        for (int s = 0; s < 4; ++s) {
            float acc = sb3[s];
            #pragma unroll
            for (int j = 0; j < 4; ++j) acc = fmaf(sh[j], sw3[s * 4 + j], acc);
            t3[i][s] = acc;
        }
    }
    #pragma unroll
    for (int w = 0; w < 16; ++w) {
        float o4[4];
        #pragma unroll
        for (int s = 0; s < 4; ++s) {
            float acc = sb4[w];
            #pragma unroll
            for (int j = 0; j < 8; ++j) {
                int f = s * 8 + j;
                acc = fmaf(t3[f >> 2][f & 3], sw4[w * 8 + j], acc);
            }
            o4[s] = acc;
        }
        float4 vv = {o4[0], o4[1], o4[2], o4[3]};
        ((float4*)seg_out)[b * 8192 + t * 16 + w] = vv;
    }

    // ======== cls head ========
    #pragma unroll
    for (int g = 0; g < 8; ++g)
        #pragma unroll
        for (int s = 0; s < 4; ++s) {
            float acc = cb1[s];
            #pragma unroll
            for (int k = 0; k < 8; ++k) acc = fmaf(y[g * 8 + k], cw1[s * 8 + k], acc);
            t1[g][s] = acc;
        }
    #pragma unroll
    for (int i = 0; i < 8; ++i) {
        float sh[4];
        #pragma unroll
        for (int j = 0; j < 4; ++j) { int m = i * 4 + j; sh[j] = t1[m & 7][m >> 3]; }
        #pragma unroll
        for (int s = 0; s < 4; ++s) {
            float acc = cb2[s];
            #pragma unroll
            for (int j = 0; j < 4; ++j) acc = fmaf(sh[j], cw2[s * 4 + j], acc);
            t2[i][s] = acc;
        }
    }
    #pragma unroll
    for (int i = 0; i < 8; ++i) {
        float sh[4];
        #pragma unroll
        for (int j = 0; j < 4; ++j) { int m = i * 4 + j; sh[j] = t2[m & 7][m >> 3]; }
        #pragma unroll
        for (int s = 0; s < 4; ++s) {
            float acc = cb3[s];
            #pragma unroll
            for (int j = 0; j < 4; ++j) acc = fmaf(sh[j], cw3[s * 4 + j], acc);
            t3[i][s] = fmaxf(acc, 0.f);
        }
    }
    float cc[4];
    #pragma unroll
    for (int c = 0; c < 4; ++c) {
        float acc = cb4[c];
        #pragma unroll
        for (int k = 0; k < 32; ++k)
            acc = fmaf(t3[k >> 2][k & 3], cw4[c * 32 + k], acc);
        cc[c] = acc;
    }
    float4 cv = {cc[0], cc[1], cc[2], cc[3]};
    ((float4*)cls_tmp)[idx] = cv;
}

// ---------------- cls mean over windows ----------------
__global__ __launch_bounds__(256) void cls_reduce_kernel(
    const float* __restrict__ cls_tmp, float* __restrict__ cls_out)
{
    const int tid = threadIdx.x;
    const int b = tid >> 2, q = tid & 3;
    float ax = 0.f, ay = 0.f, az = 0.f, aw = 0.f;
    for (int t = q; t < 512; t += 4) {
        float4 v = ((const float4*)cls_tmp)[b * 512 + t];
        ax += v.x; ay += v.y; az += v.z; aw += v.w;
    }
    ax += __shfl_xor(ax, 1); ay += __shfl_xor(ay, 1);
    az += __shfl_xor(az, 1); aw += __shfl_xor(aw, 1);
    ax += __shfl_xor(ax, 2); ay += __shfl_xor(ay, 2);
    az += __shfl_xor(az, 2); aw += __shfl_xor(aw, 2);
    if (q == 0) {
        float4 rv = {ax / 512.f, ay / 512.f, az / 512.f, aw / 512.f};
        ((float4*)cls_out)[b] = rv;
    }
}

// ---------------- avg_pool1d(k=11,s=1) with 10 zero history ----------------
__global__ __launch_bounds__(256) void pool_kernel(
    const float* __restrict__ seg, float* __restrict__ pool_out)
{
    const int idx = blockIdx.x * 256 + threadIdx.x;
    if (idx >= 64 * 8192) return;
    const int b = idx >> 13, ll = idx & 8191;
    float ax = 0.f, ay = 0.f, az = 0.f, aw = 0.f;
    int j0 = ll - 10; if (j0 < 0) j0 = 0;
    for (int j = j0; j <= ll; ++j) {
        float4 v = ((const float4*)seg)[b * 8192 + j];
        ax += v.x; ay += v.y; az += v.z; aw += v.w;
    }
    const float inv = 1.0f / 11.0f;
    float4 ov = {ax * inv, ay * inv, az * inv, aw * inv};
    ((float4*)pool_out)[idx] = ov;
}

extern "C" void kernel_launch(void* const* d_in, const int* in_sizes, int n_in,
                              void* d_out, int out_size, void* d_ws, size_t ws_size,
                              hipStream_t stream)
{
    const float* x    = (const float*)d_in[0];
    const float* h0   = (const float*)d_in[1];
    const float* w_ih = (const float*)d_in[2];
    const float* w_hh = (const float*)d_in[3];
    const float* bihp = (const float*)d_in[4];
    const float* bhhp = (const float*)d_in[5];
    const float* aw1  = (const float*)d_in[6];
    const float* aw2  = (const float*)d_in[7];
    const float* aw3  = (const float*)d_in[8];
    const float* aw4  = (const float*)d_in[9];
    const float* sw1  = (const float*)d_in[10];
    const float* sb1  = (const float*)d_in[11];
    const float* sw2  = (const float*)d_in[12];
    const float* sb2  = (const float*)d_in[13];
    const float* sw3  = (const float*)d_in[14];
    const float* sb3  = (const float*)d_in[15];
    const float* sw4  = (const float*)d_in[16];
    const float* sb4  = (const float*)d_in[17];
    const float* cw1  = (const float*)d_in[18];
    const float* cb1  = (const float*)d_in[19];
    const float* cw2  = (const float*)d_in[20];
    const float* cb2  = (const float*)d_in[21];
    const float* cw3  = (const float*)d_in[22];
    const float* cb3  = (const float*)d_in[23];
    const float* cw4  = (const float*)d_in[24];
    const float* cb4  = (const float*)d_in[25];

    float* out      = (float*)d_out;
    float* pool_out = out;                 // (64,8192,4)
    float* cls_out  = out + 2097152;       // (64,4)
    float* ys_out   = out + 2097408;       // (64,512,64)
    float* hfin     = out + 4194560;       // (8,64,64)
    float* seg_out  = out + 4227328;       // (64,8192,4)
    float* cls_tmp  = pool_out;            // staged in pool region, overwritten last

    unsigned* flags  = (unsigned*)d_ws;                   // 32 KB header
    unsigned* ring32 = (unsigned*)((char*)d_ws + 32768);  // 56 x D x 256 u32

    // ring depth: unique slot per timestep if ws allows (no back-pressure)
    size_t slots = (ws_size > 32768) ? (ws_size - 32768) / (56ull * 256 * 4) : 8;
    int D = 512;
    if (slots < 512) {
        D = 8;
        while ((size_t)(D * 2) <= slots && D < 512) D <<= 1;
    }

    init_flags<<<32, 256, 0, stream>>>(flags);
    rnn_kernel<<<64, 256, 0, stream>>>(x, h0, w_ih, w_hh, bihp, bhhp,
                                       aw1, aw2, aw3, aw4, ys_out, hfin,
                                       flags, ring32, D);
    heads_kernel<<<128, 256, 0, stream>>>(ys_out, sw1, sb1, sw2, sb2, sw3, sb3, sw4, sb4,
                                          cw1, cb1, cw2, cb2, cw3, cb3, cw4, cb4,
                                          seg_out, cls_tmp);
    cls_reduce_kernel<<<1, 256, 0, stream>>>(cls_tmp, cls_out);
    pool_kernel<<<2048, 256, 0, stream>>>(seg_out, pool_out);
}